// Round 1
// baseline (1510.206 us; speedup 1.0000x reference)
//
#include <hip/hip_runtime.h>
#include <hip/hip_bf16.h>
#include <math.h>

#define B_N 16
#define C_N 512
#define T_N 2048
#define D_N 64
#define LOG2E 1.44269504088896340736f

// ---------------------------------------------------------------------------
// Kernel 1: QKV projection (1x1 conv == per-batch GEMM)
//   q[b,d,t] = sum_c wq[d,c] x[b,c,t] + bq[d]   (f32 out)
//   k[b,d,t] = sum_c wk[d,c] x[b,c,t] + bk[d]   (f32 out)
//   v[b,o,t] = sum_c wv[o,c] x[b,c,t] + bv[o]   (bf16 out)
// Tile: 64 output rows x 64 t, 256 threads, 4x4 per-thread micro-tile.
// ---------------------------------------------------------------------------
__global__ __launch_bounds__(256) void qkv_kernel(
    const float* __restrict__ x,
    const float* __restrict__ wq, const float* __restrict__ bq,
    const float* __restrict__ wk, const float* __restrict__ bk,
    const float* __restrict__ wv, const float* __restrict__ bv,
    float* __restrict__ qf, float* __restrict__ kf,
    unsigned short* __restrict__ vh)
{
    const int t0 = blockIdx.x * 64;
    const int ob = blockIdx.y;      // 0=q, 1=k, 2..9 = v row-blocks
    const int b  = blockIdx.z;

    const float* W; const float* bias; int orow0;
    if (ob == 0)      { W = wq; bias = bq; orow0 = 0; }
    else if (ob == 1) { W = wk; bias = bk; orow0 = 0; }
    else              { W = wv; bias = bv; orow0 = (ob - 2) * 64; }

    __shared__ float Xs[32][64];   // [cc][tt]
    __shared__ float Wt[32][68];   // [cc][oo], pad 68 keeps float4 16B-aligned

    const int tid = threadIdx.x;
    const int tx = tid & 15;       // t micro index (x4)
    const int ty = tid >> 4;       // o micro index (x4)

    float acc[4][4];
    #pragma unroll
    for (int i = 0; i < 4; ++i)
        #pragma unroll
        for (int j = 0; j < 4; ++j) acc[i][j] = 0.f;

    const float* xb = x + (size_t)b * C_N * T_N;

    for (int c0 = 0; c0 < C_N; c0 += 32) {
        {   // stage X tile 32c x 64t (coalesced along t)
            const int lt = tid & 63, lc = tid >> 6;
            #pragma unroll
            for (int r = 0; r < 8; ++r)
                Xs[lc + r * 4][lt] = xb[(size_t)(c0 + lc + r * 4) * T_N + t0 + lt];
        }
        {   // stage W tile 64o x 32c, transposed into Wt[cc][oo]
            const int lc = tid & 31, lo = tid >> 5;
            #pragma unroll
            for (int r = 0; r < 8; ++r)
                Wt[lc][lo + r * 8] = W[(size_t)(orow0 + lo + r * 8) * C_N + c0 + lc];
        }
        __syncthreads();
        #pragma unroll
        for (int cc = 0; cc < 32; ++cc) {
            const float4 xv = *(const float4*)&Xs[cc][tx * 4];
            const float4 wv4 = *(const float4*)&Wt[cc][ty * 4];
            const float wv_[4] = {wv4.x, wv4.y, wv4.z, wv4.w};
            const float xv_[4] = {xv.x, xv.y, xv.z, xv.w};
            #pragma unroll
            for (int i = 0; i < 4; ++i)
                #pragma unroll
                for (int j = 0; j < 4; ++j)
                    acc[i][j] += wv_[i] * xv_[j];
        }
        __syncthreads();
    }

    // epilogue: add bias, store
    #pragma unroll
    for (int i = 0; i < 4; ++i) {
        const int oo = ty * 4 + i;
        const float bb = bias[orow0 + oo];
        float4 v4;
        v4.x = acc[i][0] + bb; v4.y = acc[i][1] + bb;
        v4.z = acc[i][2] + bb; v4.w = acc[i][3] + bb;
        if (ob == 0) {
            *(float4*)&qf[((size_t)b * D_N + oo) * T_N + t0 + tx * 4] = v4;
        } else if (ob == 1) {
            *(float4*)&kf[((size_t)b * D_N + oo) * T_N + t0 + tx * 4] = v4;
        } else {
            ushort4 h;
            __hip_bfloat16 h0 = __float2bfloat16(v4.x);
            __hip_bfloat16 h1 = __float2bfloat16(v4.y);
            __hip_bfloat16 h2 = __float2bfloat16(v4.z);
            __hip_bfloat16 h3 = __float2bfloat16(v4.w);
            h.x = *(unsigned short*)&h0; h.y = *(unsigned short*)&h1;
            h.z = *(unsigned short*)&h2; h.w = *(unsigned short*)&h3;
            *(ushort4*)&vh[((size_t)b * C_N + orow0 + oo) * T_N + t0 + tx * 4] = h;
        }
    }
}

// ---------------------------------------------------------------------------
// Kernel 2: flash-style attention + PV + residual
// Block: one batch b, 32 query positions (t0..t0+31), all 512 channels.
// Online softmax over s in tiles of 32. acc[8][8] per thread (c x tt).
// ---------------------------------------------------------------------------
__global__ __launch_bounds__(256) void attn_kernel(
    const float* __restrict__ x,
    const float* __restrict__ qf, const float* __restrict__ kf,
    const unsigned short* __restrict__ vh,
    const float* __restrict__ gamma,
    float* __restrict__ out)
{
    const int t0 = blockIdx.x * 32;
    const int b  = blockIdx.y;
    const int tid = threadIdx.x;

    __shared__ float Qs[64][36];          // [d][tt], pad 36: float4-aligned
    __shared__ float Ks[64][33];          // [d][ss]
    __shared__ float Ps[32][36];          // [ss][tt], pad 36: float4-aligned
    __shared__ unsigned short Vs[512][34];// [c][ss] bf16
    __shared__ float r_lds[32];
    __shared__ float l_lds[32];

    const float* qb = qf + (size_t)b * D_N * T_N;
    const float* kb = kf + (size_t)b * D_N * T_N;
    const unsigned short* vb = vh + (size_t)b * C_N * T_N;

    {   // stage Q tile 64d x 32t (once)
        const int lt = tid & 31, ld = tid >> 5;
        #pragma unroll
        for (int r = 0; r < 8; ++r)
            Qs[ld + r * 8][lt] = qb[(size_t)(ld + r * 8) * T_N + t0 + lt];
    }

    const int ssL = tid & 31, tgL = tid >> 5;  // logits role: rows tgL*4..+3
    const int cg  = tid & 63, tgP = tid >> 6;  // PV role: c=cg+64i, rows tgP*8..+7

    float m_run[4], l_run[4];
    #pragma unroll
    for (int j = 0; j < 4; ++j) { m_run[j] = -INFINITY; l_run[j] = 0.f; }

    float acc[8][8];
    #pragma unroll
    for (int i = 0; i < 8; ++i)
        #pragma unroll
        for (int j = 0; j < 8; ++j) acc[i][j] = 0.f;

    for (int s0 = 0; s0 < T_N; s0 += 32) {
        __syncthreads();   // previous iteration done reading Ks/Vs/Ps
        {   // stage K tile 64d x 32s (f32)
            const int ls = tid & 31, ld = tid >> 5;
            #pragma unroll
            for (int r = 0; r < 8; ++r)
                Ks[ld + r * 8][ls] = kb[(size_t)(ld + r * 8) * T_N + s0 + ls];
        }
        {   // stage V tile 512c x 32s (bf16, 2 elems per 4B load)
            const int ls2 = tid & 15, lc = tid >> 4;
            #pragma unroll
            for (int r = 0; r < 32; ++r) {
                const int c = lc + r * 16;
                const unsigned int w =
                    *(const unsigned int*)&vb[(size_t)c * T_N + s0 + ls2 * 2];
                *(unsigned int*)&Vs[c][ls2 * 2] = w;
            }
        }
        __syncthreads();

        // ---- logits: L[tt][ss] = sum_d Q[d][tt] * K[d][ss]
        float lg[4] = {0.f, 0.f, 0.f, 0.f};
        #pragma unroll 8
        for (int d = 0; d < 64; ++d) {
            const float kv = Ks[d][ssL];
            const float4 q4 = *(const float4*)&Qs[d][tgL * 4];
            lg[0] += q4.x * kv; lg[1] += q4.y * kv;
            lg[2] += q4.z * kv; lg[3] += q4.w * kv;
        }

        // ---- online softmax (row reduce over 32 lanes = ss)
        float rs[4];
        #pragma unroll
        for (int j = 0; j < 4; ++j) {
            float mx = lg[j];
            #pragma unroll
            for (int off = 16; off >= 1; off >>= 1)
                mx = fmaxf(mx, __shfl_xor(mx, off));
            const float m_new = fmaxf(m_run[j], mx);
            const float r = exp2f((m_run[j] - m_new) * LOG2E);
            const float p = exp2f((lg[j] - m_new) * LOG2E);
            float sum = p;
            #pragma unroll
            for (int off = 16; off >= 1; off >>= 1)
                sum += __shfl_xor(sum, off);
            l_run[j] = l_run[j] * r + sum;
            m_run[j] = m_new;
            rs[j] = r;
            Ps[ssL][tgL * 4 + j] = p;
        }
        if (ssL == 0) {
            #pragma unroll
            for (int j = 0; j < 4; ++j) {
                r_lds[tgL * 4 + j] = rs[j];
                l_lds[tgL * 4 + j] = l_run[j];
            }
        }
        __syncthreads();

        // ---- rescale + PV accumulate
        float rr[8];
        #pragma unroll
        for (int j = 0; j < 8; ++j) rr[j] = r_lds[tgP * 8 + j];
        #pragma unroll
        for (int i = 0; i < 8; ++i)
            #pragma unroll
            for (int j = 0; j < 8; ++j) acc[i][j] *= rr[j];

        for (int ss = 0; ss < 32; ++ss) {
            const float4 pa = *(const float4*)&Ps[ss][tgP * 8];
            const float4 pb = *(const float4*)&Ps[ss][tgP * 8 + 4];
            const float pv[8] = {pa.x, pa.y, pa.z, pa.w, pb.x, pb.y, pb.z, pb.w};
            #pragma unroll
            for (int i = 0; i < 8; ++i) {
                const unsigned int ui = ((unsigned int)Vs[cg + (i << 6)][ss]) << 16;
                const float vv = __uint_as_float(ui);
                #pragma unroll
                for (int j = 0; j < 8; ++j) acc[i][j] += vv * pv[j];
            }
        }
    }

    // ---- epilogue: out = gamma * acc / l + x, transposed via LDS for coalescing
    const float g = gamma[0];
    float invl[8];
    // l_lds final (written before last mid-loop barrier; PV phase followed it)
    #pragma unroll
    for (int j = 0; j < 8; ++j) invl[j] = 1.0f / l_lds[tgP * 8 + j];

    float (*Os)[33] = Ks;   // reuse K tile LDS
    const float* xb = x + (size_t)b * C_N * T_N;
    float* ob_ = out + (size_t)b * C_N * T_N;

    for (int i = 0; i < 8; ++i) {
        __syncthreads();
        #pragma unroll
        for (int j = 0; j < 8; ++j)
            Os[cg][tgP * 8 + j] = acc[i][j] * invl[j];
        __syncthreads();
        const int lt = tid & 31, lc0 = tid >> 5;
        #pragma unroll
        for (int r = 0; r < 8; ++r) {
            const int c = (i << 6) + lc0 + r * 8;
            const size_t idx = (size_t)c * T_N + t0 + lt;
            ob_[idx] = g * Os[lc0 + r * 8][lt] + xb[idx];
        }
    }
}

// ---------------------------------------------------------------------------
extern "C" void kernel_launch(void* const* d_in, const int* in_sizes, int n_in,
                              void* d_out, int out_size, void* d_ws, size_t ws_size,
                              hipStream_t stream)
{
    const float* x     = (const float*)d_in[0];
    const float* wq    = (const float*)d_in[1];
    const float* bq    = (const float*)d_in[2];
    const float* wk    = (const float*)d_in[3];
    const float* bk    = (const float*)d_in[4];
    const float* wv    = (const float*)d_in[5];
    const float* bv    = (const float*)d_in[6];
    const float* gamma = (const float*)d_in[7];
    float* out = (float*)d_out;

    // ws layout: q f32 [B][64][T] | k f32 [B][64][T] | v bf16 [B][512][T]
    float* qf = (float*)d_ws;
    float* kf = qf + (size_t)B_N * D_N * T_N;
    unsigned short* vh = (unsigned short*)(kf + (size_t)B_N * D_N * T_N);

    dim3 g1(T_N / 64, 10, B_N);
    qkv_kernel<<<g1, 256, 0, stream>>>(x, wq, bq, wk, bk, wv, bv, qf, kf, vh);

    dim3 g2(T_N / 32, B_N);
    attn_kernel<<<g2, 256, 0, stream>>>(x, qf, kf, vh, gamma, out);

    (void)in_sizes; (void)n_in; (void)out_size; (void)ws_size;
}

// Round 4
// 979.638 us; speedup vs baseline: 1.5416x; 1.5416x over previous
//
#include <hip/hip_runtime.h>
#include <hip/hip_bf16.h>
#include <math.h>

#define B_N 16
#define C_N 512
#define T_N 2048
#define D_N 64
#define LOG2E 1.44269504088896340736f

typedef __attribute__((ext_vector_type(4))) float f32x4;
typedef __attribute__((ext_vector_type(8))) __bf16 bf16x8;
typedef __attribute__((ext_vector_type(8))) unsigned short us8;
typedef __attribute__((ext_vector_type(4))) unsigned short us4;

__device__ inline f32x4 mfma16(bf16x8 a, bf16x8 b, f32x4 c) {
    return __builtin_amdgcn_mfma_f32_16x16x32_bf16(a, b, c, 0, 0, 0);
}
__device__ inline unsigned short f2bf_bits(float v) {
    return __builtin_bit_cast(unsigned short, __float2bfloat16(v));
}
__device__ inline float bfbits2f(unsigned short u) {
    unsigned int x = ((unsigned int)u) << 16;
    return __builtin_bit_cast(float, x);
}

// swizzled LDS index helpers (ushort units; XOR spreads 16B slots across banks)
#define QIDX(t,d) (((((t)<<6) | (d))) ^ ((((t)&7))<<3))   // rows of 64
#define KIDX(s,d) (((((s)<<6) | (d))) ^ ((((s)&7))<<3))   // rows of 64
#define VIDX(c,s) (((((c)<<5) | (s))) ^ ((((c)&7))<<3))   // rows of 32
#define PIDX(t,s) (((((t)<<5) | (s))) ^ ((((t)&7))<<3))   // rows of 32

// ---------------------------------------------------------------------------
// Kernel 1: QKV projection.
//   q,k -> bf16 hi/lo, layout [b][t][64]  (transposed, for MFMA A/B frags)
//   v   -> bf16,       layout [b][c][T]
// ---------------------------------------------------------------------------
__global__ __launch_bounds__(256) void qkv_kernel(
    const float* __restrict__ x,
    const float* __restrict__ wq, const float* __restrict__ bq,
    const float* __restrict__ wk, const float* __restrict__ bk,
    const float* __restrict__ wv, const float* __restrict__ bv,
    unsigned short* __restrict__ qth, unsigned short* __restrict__ qtl,
    unsigned short* __restrict__ kth, unsigned short* __restrict__ ktl,
    unsigned short* __restrict__ vh)
{
    const int t0 = blockIdx.x * 64;
    const int ob = blockIdx.y;      // 0=q, 1=k, 2..9 = v row-blocks
    const int b  = blockIdx.z;

    const float* W; const float* bias; int orow0;
    if (ob == 0)      { W = wq; bias = bq; orow0 = 0; }
    else if (ob == 1) { W = wk; bias = bk; orow0 = 0; }
    else              { W = wv; bias = bv; orow0 = (ob - 2) * 64; }

    __shared__ float Xs[32][64];   // [cc][tt]
    __shared__ float Wt[32][68];   // [cc][oo]

    const int tid = threadIdx.x;
    const int tx = tid & 15;
    const int ty = tid >> 4;

    float acc[4][4];
    #pragma unroll
    for (int i = 0; i < 4; ++i)
        #pragma unroll
        for (int j = 0; j < 4; ++j) acc[i][j] = 0.f;

    const float* xb = x + (size_t)b * C_N * T_N;

    if (ob < 2) {
        // micro mapping: i -> t (ty), j -> o (tx)  => coalesced transposed store
        for (int c0 = 0; c0 < C_N; c0 += 32) {
            {
                const int lt = tid & 63, lc = tid >> 6;
                #pragma unroll
                for (int r = 0; r < 8; ++r)
                    Xs[lc + r * 4][lt] = xb[(size_t)(c0 + lc + r * 4) * T_N + t0 + lt];
            }
            {
                const int lc = tid & 31, lo = tid >> 5;
                #pragma unroll
                for (int r = 0; r < 8; ++r)
                    Wt[lc][lo + r * 8] = W[(size_t)(orow0 + lo + r * 8) * C_N + c0 + lc];
            }
            __syncthreads();
            #pragma unroll
            for (int cc = 0; cc < 32; ++cc) {
                const float4 xv = *(const float4*)&Xs[cc][ty * 4];   // t part
                const float4 wv4 = *(const float4*)&Wt[cc][tx * 4];  // o part
                const float xv_[4] = {xv.x, xv.y, xv.z, xv.w};
                const float wv_[4] = {wv4.x, wv4.y, wv4.z, wv4.w};
                #pragma unroll
                for (int i = 0; i < 4; ++i)
                    #pragma unroll
                    for (int j = 0; j < 4; ++j)
                        acc[i][j] += xv_[i] * wv_[j];
            }
            __syncthreads();
        }
        unsigned short* dh = (ob == 0) ? qth : kth;
        unsigned short* dl = (ob == 0) ? qtl : ktl;
        const float4 b4 = *(const float4*)&bias[tx * 4];
        const float bb[4] = {b4.x, b4.y, b4.z, b4.w};
        #pragma unroll
        for (int i = 0; i < 4; ++i) {
            const int tt = ty * 4 + i;
            us4 h4, l4;
            #pragma unroll
            for (int j = 0; j < 4; ++j) {
                const float v = acc[i][j] + bb[j];
                const unsigned short hb = f2bf_bits(v);
                h4[j] = hb;
                l4[j] = f2bf_bits(v - bfbits2f(hb));
            }
            const size_t off = ((size_t)b * T_N + t0 + tt) * 64 + tx * 4;
            *(us4*)&dh[off] = h4;
            *(us4*)&dl[off] = l4;
        }
    } else {
        // micro mapping: i -> o (ty), j -> t (tx)  => coalesced [c][t] store
        for (int c0 = 0; c0 < C_N; c0 += 32) {
            {
                const int lt = tid & 63, lc = tid >> 6;
                #pragma unroll
                for (int r = 0; r < 8; ++r)
                    Xs[lc + r * 4][lt] = xb[(size_t)(c0 + lc + r * 4) * T_N + t0 + lt];
            }
            {
                const int lc = tid & 31, lo = tid >> 5;
                #pragma unroll
                for (int r = 0; r < 8; ++r)
                    Wt[lc][lo + r * 8] = W[(size_t)(orow0 + lo + r * 8) * C_N + c0 + lc];
            }
            __syncthreads();
            #pragma unroll
            for (int cc = 0; cc < 32; ++cc) {
                const float4 xv = *(const float4*)&Xs[cc][tx * 4];   // t part
                const float4 wv4 = *(const float4*)&Wt[cc][ty * 4];  // o part
                const float xv_[4] = {xv.x, xv.y, xv.z, xv.w};
                const float wv_[4] = {wv4.x, wv4.y, wv4.z, wv4.w};
                #pragma unroll
                for (int i = 0; i < 4; ++i)
                    #pragma unroll
                    for (int j = 0; j < 4; ++j)
                        acc[i][j] += wv_[i] * xv_[j];
            }
            __syncthreads();
        }
        #pragma unroll
        for (int i = 0; i < 4; ++i) {
            const int oo = ty * 4 + i;
            const float bb = bias[orow0 + oo];
            us4 h4;
            #pragma unroll
            for (int j = 0; j < 4; ++j)
                h4[j] = f2bf_bits(acc[i][j] + bb);
            *(us4*)&vh[((size_t)b * C_N + orow0 + oo) * T_N + t0 + tx * 4] = h4;
        }
    }
}

// ---------------------------------------------------------------------------
// Kernel 2: MFMA flash attention + PV + residual.
// Block: (batch, 64 queries). 8 waves: wave = (t-block tb of 16) x (c-half ch).
// s-loop in tiles of 32. QK^T via 3-way bf16 hi/lo split MFMAs. Softmax
// in-register. P through per-wave swizzled LDS. PV: 16 MFMAs/wave/step.
// ---------------------------------------------------------------------------
__global__ __launch_bounds__(512, 4) void attn_mfma_kernel(
    const float* __restrict__ x,
    const unsigned short* __restrict__ qth, const unsigned short* __restrict__ qtl,
    const unsigned short* __restrict__ kth, const unsigned short* __restrict__ ktl,
    const unsigned short* __restrict__ vh,
    const float* __restrict__ gamma,
    float* __restrict__ out)
{
    __shared__ unsigned short Qh_s[64 * 64];
    __shared__ unsigned short Ql_s[64 * 64];
    __shared__ unsigned short Kh_s[32 * 64];
    __shared__ unsigned short Kl_s[32 * 64];
    __shared__ unsigned short V_s[512 * 32];
    __shared__ unsigned short P_s[8 * 16 * 32];

    const int tid  = threadIdx.x;
    const int wave = tid >> 6;
    const int lane = tid & 63;
    const int ln   = lane & 15;
    const int lg   = lane >> 4;
    const int t0   = blockIdx.x * 64;
    const int b    = blockIdx.y;

    const int tb = wave & 3;        // t-block (16 rows)
    const int ch = wave >> 2;       // c-half  (256 cols)

    // ---- stage Q (hi & lo), 64 rows x 64 d, once
    {
        const int r = tid >> 3, c8 = (tid & 7) * 8;
        const size_t off = ((size_t)b * T_N + t0 + r) * 64 + c8;
        const int idx = QIDX(r, c8);
        *(us8*)&Qh_s[idx] = *(const us8*)&qth[off];
        *(us8*)&Ql_s[idx] = *(const us8*)&qtl[off];
    }

    const int trow = tb * 16 + ln;

    float m_run[4], l_run[4];
    #pragma unroll
    for (int r = 0; r < 4; ++r) { m_run[r] = -INFINITY; l_run[r] = 0.f; }

    f32x4 acc[16];
    #pragma unroll
    for (int ct = 0; ct < 16; ++ct) acc[ct] = (f32x4){0.f, 0.f, 0.f, 0.f};

    for (int s0 = 0; s0 < T_N; s0 += 32) {
        __syncthreads();   // prior reads of K/V done
        {   // stage K hi (waves 0-3) / lo (waves 4-7): 32 rows x 64 d
            const int t2 = tid & 255;
            const int r = t2 >> 3, c8 = (t2 & 7) * 8;
            const size_t off = ((size_t)b * T_N + s0 + r) * 64 + c8;
            const int idx = KIDX(r, c8);
            if (tid < 256) *(us8*)&Kh_s[idx] = *(const us8*)&kth[off];
            else           *(us8*)&Kl_s[idx] = *(const us8*)&ktl[off];
        }
        {   // stage V: 512 c x 32 s
            #pragma unroll
            for (int i = 0; i < 4; ++i) {
                const int chunk = tid + i * 512;
                const int c = chunk >> 2, s8 = (chunk & 3) * 8;
                *(us8*)&V_s[VIDX(c, s8)] =
                    *(const us8*)&vh[((size_t)b * C_N + c) * T_N + s0 + s8];
            }
        }
        __syncthreads();

        // ---- QK^T: S[2] tiles of 16t x 16s, split-3 for precision
        f32x4 S[2];
        S[0] = (f32x4){0.f, 0.f, 0.f, 0.f};
        S[1] = (f32x4){0.f, 0.f, 0.f, 0.f};
        #pragma unroll
        for (int kk = 0; kk < 2; ++kk) {
            const int d0 = kk * 32 + lg * 8;
            const bf16x8 ah = __builtin_bit_cast(bf16x8, *(const us8*)&Qh_s[QIDX(trow, d0)]);
            const bf16x8 al = __builtin_bit_cast(bf16x8, *(const us8*)&Ql_s[QIDX(trow, d0)]);
            #pragma unroll
            for (int st = 0; st < 2; ++st) {
                const int srow = st * 16 + ln;
                const bf16x8 bh = __builtin_bit_cast(bf16x8, *(const us8*)&Kh_s[KIDX(srow, d0)]);
                const bf16x8 bl = __builtin_bit_cast(bf16x8, *(const us8*)&Kl_s[KIDX(srow, d0)]);
                S[st] = mfma16(ah, bh, S[st]);
                S[st] = mfma16(ah, bl, S[st]);
                S[st] = mfma16(al, bh, S[st]);
            }
        }

        // ---- online softmax (rows t = lg*4 + r; reduce over 16 col-lanes)
        float rs[4];
        #pragma unroll
        for (int r = 0; r < 4; ++r) {
            float mx = fmaxf(S[0][r], S[1][r]);
            mx = fmaxf(mx, __shfl_xor(mx, 1));
            mx = fmaxf(mx, __shfl_xor(mx, 2));
            mx = fmaxf(mx, __shfl_xor(mx, 4));
            mx = fmaxf(mx, __shfl_xor(mx, 8));
            const float m_new = fmaxf(m_run[r], mx);
            const float rr = exp2f((m_run[r] - m_new) * LOG2E);
            const float p0 = exp2f((S[0][r] - m_new) * LOG2E);
            const float p1 = exp2f((S[1][r] - m_new) * LOG2E);
            float sm = p0 + p1;
            sm += __shfl_xor(sm, 1);
            sm += __shfl_xor(sm, 2);
            sm += __shfl_xor(sm, 4);
            sm += __shfl_xor(sm, 8);
            l_run[r] = l_run[r] * rr + sm;
            m_run[r] = m_new;
            rs[r] = rr;
            const int t = lg * 4 + r;
            P_s[wave * 512 + PIDX(t, ln)]      = f2bf_bits(p0);
            P_s[wave * 512 + PIDX(t, 16 + ln)] = f2bf_bits(p1);
        }

        // ---- rescale O, then PV
        #pragma unroll
        for (int ct = 0; ct < 16; ++ct)
            #pragma unroll
            for (int r = 0; r < 4; ++r) acc[ct][r] *= rs[r];

        const bf16x8 pa = __builtin_bit_cast(bf16x8,
            *(const us8*)&P_s[wave * 512 + PIDX(ln, lg * 8)]);
        #pragma unroll
        for (int ct = 0; ct < 16; ++ct) {
            const int c = ch * 256 + ct * 16 + ln;
            const bf16x8 bv = __builtin_bit_cast(bf16x8, *(const us8*)&V_s[VIDX(c, lg * 8)]);
            acc[ct] = mfma16(pa, bv, acc[ct]);
        }
    }

    // ---- epilogue: out = gamma * O / l + x   (regs of acc are consecutive t)
    const float g = gamma[0];
    float invl[4];
    #pragma unroll
    for (int r = 0; r < 4; ++r) invl[r] = 1.0f / l_run[r];

    const float* xb = x + (size_t)b * C_N * T_N;
    float* ob_ = out + (size_t)b * C_N * T_N;
    const int tl0 = t0 + tb * 16 + lg * 4;

    #pragma unroll
    for (int ct = 0; ct < 16; ++ct) {
        const int c = ch * 256 + ct * 16 + ln;
        const size_t off = (size_t)c * T_N + tl0;
        const float4 xv = *(const float4*)&xb[off];
        float4 o4;
        o4.x = g * acc[ct][0] * invl[0] + xv.x;
        o4.y = g * acc[ct][1] * invl[1] + xv.y;
        o4.z = g * acc[ct][2] * invl[2] + xv.z;
        o4.w = g * acc[ct][3] * invl[3] + xv.w;
        *(float4*)&ob_[off] = o4;
    }
}

// ---------------------------------------------------------------------------
extern "C" void kernel_launch(void* const* d_in, const int* in_sizes, int n_in,
                              void* d_out, int out_size, void* d_ws, size_t ws_size,
                              hipStream_t stream)
{
    const float* x     = (const float*)d_in[0];
    const float* wq    = (const float*)d_in[1];
    const float* bq    = (const float*)d_in[2];
    const float* wk    = (const float*)d_in[3];
    const float* bk    = (const float*)d_in[4];
    const float* wv    = (const float*)d_in[5];
    const float* bv    = (const float*)d_in[6];
    const float* gamma = (const float*)d_in[7];
    float* out = (float*)d_out;

    // ws layout (ushorts): qth | qtl | kth | ktl  [b][t][64] each, then v [b][c][T]
    unsigned short* qth = (unsigned short*)d_ws;
    unsigned short* qtl = qth + (size_t)B_N * T_N * 64;
    unsigned short* kth = qtl + (size_t)B_N * T_N * 64;
    unsigned short* ktl = kth + (size_t)B_N * T_N * 64;
    unsigned short* vh  = ktl + (size_t)B_N * T_N * 64;

    dim3 g1(T_N / 64, 10, B_N);
    qkv_kernel<<<g1, 256, 0, stream>>>(x, wq, bq, wk, bk, wv, bv,
                                       qth, qtl, kth, ktl, vh);

    dim3 g2(T_N / 64, B_N);
    attn_mfma_kernel<<<g2, 512, 0, stream>>>(x, qth, qtl, kth, ktl, vh, gamma, out);

    (void)in_sizes; (void)n_in; (void)out_size; (void)ws_size;
}

// Round 5
// 935.597 us; speedup vs baseline: 1.6142x; 1.0471x over previous
//
#include <hip/hip_runtime.h>
#include <hip/hip_bf16.h>
#include <math.h>

#define B_N 16
#define C_N 512
#define T_N 2048
#define D_N 64
#define LOG2E 1.44269504088896340736f

typedef __attribute__((ext_vector_type(4))) float f32x4;
typedef __attribute__((ext_vector_type(8))) __bf16 bf16x8;
typedef __attribute__((ext_vector_type(8))) unsigned short us8;
typedef __attribute__((ext_vector_type(4))) unsigned short us4;

__device__ inline f32x4 mfma16(bf16x8 a, bf16x8 b, f32x4 c) {
    return __builtin_amdgcn_mfma_f32_16x16x32_bf16(a, b, c, 0, 0, 0);
}
__device__ inline unsigned short f2bf_bits(float v) {
    return __builtin_bit_cast(unsigned short, __float2bfloat16(v));
}
__device__ inline float bfbits2f(unsigned short u) {
    unsigned int x = ((unsigned int)u) << 16;
    return __builtin_bit_cast(float, x);
}

// swizzled LDS index helpers (ushort units; XOR spreads 16B slots across banks)
#define QIDX(t,d) (((((t)<<6) | (d))) ^ ((((t)&7))<<3))   // rows of 64
#define KIDX(s,d) (((((s)<<6) | (d))) ^ ((((s)&7))<<3))   // rows of 64
#define VIDX(c,s) (((((c)<<5) | (s))) ^ ((((c)&7))<<3))   // rows of 32
#define PIDX(t,s) (((((t)<<5) | (s))) ^ ((((t)&7))<<3))   // rows of 32

// ---------------------------------------------------------------------------
// Kernel 1: QKV projection.  (unchanged from round 4)
//   q,k -> bf16 hi/lo, layout [b][t][64]  (transposed, for MFMA A/B frags)
//   v   -> bf16,       layout [b][c][T]
// ---------------------------------------------------------------------------
__global__ __launch_bounds__(256) void qkv_kernel(
    const float* __restrict__ x,
    const float* __restrict__ wq, const float* __restrict__ bq,
    const float* __restrict__ wk, const float* __restrict__ bk,
    const float* __restrict__ wv, const float* __restrict__ bv,
    unsigned short* __restrict__ qth, unsigned short* __restrict__ qtl,
    unsigned short* __restrict__ kth, unsigned short* __restrict__ ktl,
    unsigned short* __restrict__ vh)
{
    const int t0 = blockIdx.x * 64;
    const int ob = blockIdx.y;      // 0=q, 1=k, 2..9 = v row-blocks
    const int b  = blockIdx.z;

    const float* W; const float* bias; int orow0;
    if (ob == 0)      { W = wq; bias = bq; orow0 = 0; }
    else if (ob == 1) { W = wk; bias = bk; orow0 = 0; }
    else              { W = wv; bias = bv; orow0 = (ob - 2) * 64; }

    __shared__ float Xs[32][64];   // [cc][tt]
    __shared__ float Wt[32][68];   // [cc][oo]

    const int tid = threadIdx.x;
    const int tx = tid & 15;
    const int ty = tid >> 4;

    float acc[4][4];
    #pragma unroll
    for (int i = 0; i < 4; ++i)
        #pragma unroll
        for (int j = 0; j < 4; ++j) acc[i][j] = 0.f;

    const float* xb = x + (size_t)b * C_N * T_N;

    if (ob < 2) {
        // micro mapping: i -> t (ty), j -> o (tx)  => coalesced transposed store
        for (int c0 = 0; c0 < C_N; c0 += 32) {
            {
                const int lt = tid & 63, lc = tid >> 6;
                #pragma unroll
                for (int r = 0; r < 8; ++r)
                    Xs[lc + r * 4][lt] = xb[(size_t)(c0 + lc + r * 4) * T_N + t0 + lt];
            }
            {
                const int lc = tid & 31, lo = tid >> 5;
                #pragma unroll
                for (int r = 0; r < 8; ++r)
                    Wt[lc][lo + r * 8] = W[(size_t)(orow0 + lo + r * 8) * C_N + c0 + lc];
            }
            __syncthreads();
            #pragma unroll
            for (int cc = 0; cc < 32; ++cc) {
                const float4 xv = *(const float4*)&Xs[cc][ty * 4];   // t part
                const float4 wv4 = *(const float4*)&Wt[cc][tx * 4];  // o part
                const float xv_[4] = {xv.x, xv.y, xv.z, xv.w};
                const float wv_[4] = {wv4.x, wv4.y, wv4.z, wv4.w};
                #pragma unroll
                for (int i = 0; i < 4; ++i)
                    #pragma unroll
                    for (int j = 0; j < 4; ++j)
                        acc[i][j] += xv_[i] * wv_[j];
            }
            __syncthreads();
        }
        unsigned short* dh = (ob == 0) ? qth : kth;
        unsigned short* dl = (ob == 0) ? qtl : ktl;
        const float4 b4 = *(const float4*)&bias[tx * 4];
        const float bb[4] = {b4.x, b4.y, b4.z, b4.w};
        #pragma unroll
        for (int i = 0; i < 4; ++i) {
            const int tt = ty * 4 + i;
            us4 h4, l4;
            #pragma unroll
            for (int j = 0; j < 4; ++j) {
                const float v = acc[i][j] + bb[j];
                const unsigned short hb = f2bf_bits(v);
                h4[j] = hb;
                l4[j] = f2bf_bits(v - bfbits2f(hb));
            }
            const size_t off = ((size_t)b * T_N + t0 + tt) * 64 + tx * 4;
            *(us4*)&dh[off] = h4;
            *(us4*)&dl[off] = l4;
        }
    } else {
        // micro mapping: i -> o (ty), j -> t (tx)  => coalesced [c][t] store
        for (int c0 = 0; c0 < C_N; c0 += 32) {
            {
                const int lt = tid & 63, lc = tid >> 6;
                #pragma unroll
                for (int r = 0; r < 8; ++r)
                    Xs[lc + r * 4][lt] = xb[(size_t)(c0 + lc + r * 4) * T_N + t0 + lt];
            }
            {
                const int lc = tid & 31, lo = tid >> 5;
                #pragma unroll
                for (int r = 0; r < 8; ++r)
                    Wt[lc][lo + r * 8] = W[(size_t)(orow0 + lo + r * 8) * C_N + c0 + lc];
            }
            __syncthreads();
            #pragma unroll
            for (int cc = 0; cc < 32; ++cc) {
                const float4 xv = *(const float4*)&Xs[cc][tx * 4];   // t part
                const float4 wv4 = *(const float4*)&Wt[cc][ty * 4];  // o part
                const float xv_[4] = {xv.x, xv.y, xv.z, xv.w};
                const float wv_[4] = {wv4.x, wv4.y, wv4.z, wv4.w};
                #pragma unroll
                for (int i = 0; i < 4; ++i)
                    #pragma unroll
                    for (int j = 0; j < 4; ++j)
                        acc[i][j] += wv_[i] * xv_[j];
            }
            __syncthreads();
        }
        #pragma unroll
        for (int i = 0; i < 4; ++i) {
            const int oo = ty * 4 + i;
            const float bb = bias[orow0 + oo];
            us4 h4;
            #pragma unroll
            for (int j = 0; j < 4; ++j)
                h4[j] = f2bf_bits(acc[i][j] + bb);
            *(us4*)&vh[((size_t)b * C_N + orow0 + oo) * T_N + t0 + tx * 4] = h4;
        }
    }
}

// ---------------------------------------------------------------------------
// Kernel 2: MFMA flash attention + PV + residual.
// Same structure as round 4; ONLY change: 1-D grid with XCD-aware remap so
// each XCD owns 2 complete batches (64 block-slots = 2 batches x 32 t-tiles
// = 32 CUs x 2 blocks/CU). All blocks sharing a (batch,s0) K/V tile then
// share one L2 -> V fetched once per XCD instead of once per block.
// ---------------------------------------------------------------------------
__global__ __launch_bounds__(512, 4) void attn_mfma_kernel(
    const float* __restrict__ x,
    const unsigned short* __restrict__ qth, const unsigned short* __restrict__ qtl,
    const unsigned short* __restrict__ kth, const unsigned short* __restrict__ ktl,
    const unsigned short* __restrict__ vh,
    const float* __restrict__ gamma,
    float* __restrict__ out)
{
    __shared__ unsigned short Qh_s[64 * 64];
    __shared__ unsigned short Ql_s[64 * 64];
    __shared__ unsigned short Kh_s[32 * 64];
    __shared__ unsigned short Kl_s[32 * 64];
    __shared__ unsigned short V_s[512 * 32];
    __shared__ unsigned short P_s[8 * 16 * 32];

    const int tid  = threadIdx.x;
    const int wave = tid >> 6;
    const int lane = tid & 63;
    const int ln   = lane & 15;
    const int lg   = lane >> 4;

    // XCD-aware remap: linear id l -> xcd = l&7 (HW round-robins wg->XCD).
    // slot in [0,64): batch = xcd*2 + (slot&1), t-tile = slot>>1.
    const int l    = blockIdx.x;
    const int slot = l >> 3;
    const int b    = ((l & 7) << 1) | (slot & 1);
    const int t0   = (slot >> 1) * 64;

    const int tb = wave & 3;        // t-block (16 rows)
    const int ch = wave >> 2;       // c-half  (256 cols)

    // ---- stage Q (hi & lo), 64 rows x 64 d, once
    {
        const int r = tid >> 3, c8 = (tid & 7) * 8;
        const size_t off = ((size_t)b * T_N + t0 + r) * 64 + c8;
        const int idx = QIDX(r, c8);
        *(us8*)&Qh_s[idx] = *(const us8*)&qth[off];
        *(us8*)&Ql_s[idx] = *(const us8*)&qtl[off];
    }

    const int trow = tb * 16 + ln;

    float m_run[4], l_run[4];
    #pragma unroll
    for (int r = 0; r < 4; ++r) { m_run[r] = -INFINITY; l_run[r] = 0.f; }

    f32x4 acc[16];
    #pragma unroll
    for (int ct = 0; ct < 16; ++ct) acc[ct] = (f32x4){0.f, 0.f, 0.f, 0.f};

    for (int s0 = 0; s0 < T_N; s0 += 32) {
        __syncthreads();   // prior reads of K/V done
        {   // stage K hi (waves 0-3) / lo (waves 4-7): 32 rows x 64 d
            const int t2 = tid & 255;
            const int r = t2 >> 3, c8 = (t2 & 7) * 8;
            const size_t off = ((size_t)b * T_N + s0 + r) * 64 + c8;
            const int idx = KIDX(r, c8);
            if (tid < 256) *(us8*)&Kh_s[idx] = *(const us8*)&kth[off];
            else           *(us8*)&Kl_s[idx] = *(const us8*)&ktl[off];
        }
        {   // stage V: 512 c x 32 s
            #pragma unroll
            for (int i = 0; i < 4; ++i) {
                const int chunk = tid + i * 512;
                const int c = chunk >> 2, s8 = (chunk & 3) * 8;
                *(us8*)&V_s[VIDX(c, s8)] =
                    *(const us8*)&vh[((size_t)b * C_N + c) * T_N + s0 + s8];
            }
        }
        __syncthreads();

        // ---- QK^T: S[2] tiles of 16t x 16s, split-3 for precision
        f32x4 S[2];
        S[0] = (f32x4){0.f, 0.f, 0.f, 0.f};
        S[1] = (f32x4){0.f, 0.f, 0.f, 0.f};
        #pragma unroll
        for (int kk = 0; kk < 2; ++kk) {
            const int d0 = kk * 32 + lg * 8;
            const bf16x8 ah = __builtin_bit_cast(bf16x8, *(const us8*)&Qh_s[QIDX(trow, d0)]);
            const bf16x8 al = __builtin_bit_cast(bf16x8, *(const us8*)&Ql_s[QIDX(trow, d0)]);
            #pragma unroll
            for (int st = 0; st < 2; ++st) {
                const int srow = st * 16 + ln;
                const bf16x8 bh = __builtin_bit_cast(bf16x8, *(const us8*)&Kh_s[KIDX(srow, d0)]);
                const bf16x8 bl = __builtin_bit_cast(bf16x8, *(const us8*)&Kl_s[KIDX(srow, d0)]);
                S[st] = mfma16(ah, bh, S[st]);
                S[st] = mfma16(ah, bl, S[st]);
                S[st] = mfma16(al, bh, S[st]);
            }
        }

        // ---- online softmax (rows t = lg*4 + r; reduce over 16 col-lanes)
        float rs[4];
        #pragma unroll
        for (int r = 0; r < 4; ++r) {
            float mx = fmaxf(S[0][r], S[1][r]);
            mx = fmaxf(mx, __shfl_xor(mx, 1));
            mx = fmaxf(mx, __shfl_xor(mx, 2));
            mx = fmaxf(mx, __shfl_xor(mx, 4));
            mx = fmaxf(mx, __shfl_xor(mx, 8));
            const float m_new = fmaxf(m_run[r], mx);
            const float rr = exp2f((m_run[r] - m_new) * LOG2E);
            const float p0 = exp2f((S[0][r] - m_new) * LOG2E);
            const float p1 = exp2f((S[1][r] - m_new) * LOG2E);
            float sm = p0 + p1;
            sm += __shfl_xor(sm, 1);
            sm += __shfl_xor(sm, 2);
            sm += __shfl_xor(sm, 4);
            sm += __shfl_xor(sm, 8);
            l_run[r] = l_run[r] * rr + sm;
            m_run[r] = m_new;
            rs[r] = rr;
            const int t = lg * 4 + r;
            P_s[wave * 512 + PIDX(t, ln)]      = f2bf_bits(p0);
            P_s[wave * 512 + PIDX(t, 16 + ln)] = f2bf_bits(p1);
        }

        // ---- rescale O, then PV
        #pragma unroll
        for (int ct = 0; ct < 16; ++ct)
            #pragma unroll
            for (int r = 0; r < 4; ++r) acc[ct][r] *= rs[r];

        const bf16x8 pa = __builtin_bit_cast(bf16x8,
            *(const us8*)&P_s[wave * 512 + PIDX(ln, lg * 8)]);
        #pragma unroll
        for (int ct = 0; ct < 16; ++ct) {
            const int c = ch * 256 + ct * 16 + ln;
            const bf16x8 bv = __builtin_bit_cast(bf16x8, *(const us8*)&V_s[VIDX(c, lg * 8)]);
            acc[ct] = mfma16(pa, bv, acc[ct]);
        }
    }

    // ---- epilogue: out = gamma * O / l + x   (regs of acc are consecutive t)
    const float g = gamma[0];
    float invl[4];
    #pragma unroll
    for (int r = 0; r < 4; ++r) invl[r] = 1.0f / l_run[r];

    const float* xb = x + (size_t)b * C_N * T_N;
    float* ob_ = out + (size_t)b * C_N * T_N;
    const int tl0 = t0 + tb * 16 + lg * 4;

    #pragma unroll
    for (int ct = 0; ct < 16; ++ct) {
        const int c = ch * 256 + ct * 16 + ln;
        const size_t off = (size_t)c * T_N + tl0;
        const float4 xv = *(const float4*)&xb[off];
        float4 o4;
        o4.x = g * acc[ct][0] * invl[0] + xv.x;
        o4.y = g * acc[ct][1] * invl[1] + xv.y;
        o4.z = g * acc[ct][2] * invl[2] + xv.z;
        o4.w = g * acc[ct][3] * invl[3] + xv.w;
        *(float4*)&ob_[off] = o4;
    }
}

// ---------------------------------------------------------------------------
extern "C" void kernel_launch(void* const* d_in, const int* in_sizes, int n_in,
                              void* d_out, int out_size, void* d_ws, size_t ws_size,
                              hipStream_t stream)
{
    const float* x     = (const float*)d_in[0];
    const float* wq    = (const float*)d_in[1];
    const float* bq    = (const float*)d_in[2];
    const float* wk    = (const float*)d_in[3];
    const float* bk    = (const float*)d_in[4];
    const float* wv    = (const float*)d_in[5];
    const float* bv    = (const float*)d_in[6];
    const float* gamma = (const float*)d_in[7];
    float* out = (float*)d_out;

    // ws layout (ushorts): qth | qtl | kth | ktl  [b][t][64] each, then v [b][c][T]
    unsigned short* qth = (unsigned short*)d_ws;
    unsigned short* qtl = qth + (size_t)B_N * T_N * 64;
    unsigned short* kth = qtl + (size_t)B_N * T_N * 64;
    unsigned short* ktl = kth + (size_t)B_N * T_N * 64;
    unsigned short* vh  = ktl + (size_t)B_N * T_N * 64;

    dim3 g1(T_N / 64, 10, B_N);
    qkv_kernel<<<g1, 256, 0, stream>>>(x, wq, bq, wk, bk, wv, bv,
                                       qth, qtl, kth, ktl, vh);

    // 1-D grid, XCD-aware remap inside the kernel (512 = 16 batches x 32 t-tiles)
    attn_mfma_kernel<<<512, 512, 0, stream>>>(x, qth, qtl, kth, ktl, vh, gamma, out);

    (void)in_sizes; (void)n_in; (void)out_size; (void)ws_size;
}

// Round 7
// 654.187 us; speedup vs baseline: 2.3085x; 1.4302x over previous
//
#include <hip/hip_runtime.h>
#include <hip/hip_bf16.h>
#include <math.h>

#define B_N 16
#define C_N 512
#define T_N 2048
#define D_N 64
#define LOG2E 1.44269504088896340736f

typedef __attribute__((ext_vector_type(4))) float f32x4;
typedef __attribute__((ext_vector_type(8))) __bf16 bf16x8;
typedef __attribute__((ext_vector_type(8))) unsigned short us8;
typedef __attribute__((ext_vector_type(4))) unsigned short us4;

__device__ inline f32x4 mfma16(bf16x8 a, bf16x8 b, f32x4 c) {
    return __builtin_amdgcn_mfma_f32_16x16x32_bf16(a, b, c, 0, 0, 0);
}
__device__ inline unsigned short f2bf_bits(float v) {
    return __builtin_bit_cast(unsigned short, __float2bfloat16(v));
}
__device__ inline float bfbits2f(unsigned short u) {
    unsigned int x = ((unsigned int)u) << 16;
    return __builtin_bit_cast(float, x);
}

// swizzled LDS index helpers (ushort units)
#define QIDX(t,d) (((((t)<<6) | (d))) ^ ((((t)&7))<<3))   // rows of 64, in-row 16B-chunk XOR
#define KIDX(s,d) (((((s)<<6) | (d))) ^ ((((s)&7))<<3))   // rows of 64, in-row 16B-chunk XOR
#define VIDX2(c,s) (((c)<<5) | ((s) ^ (((((c)>>1))&3)<<3))) // rows of 32, in-row 2-bit chunk XOR
#define PIDX(t,s) (((((t)<<5) | (s))) ^ ((((t)&7))<<3))   // rows of 32

#define GLD_LDS(src, dst) \
    __builtin_amdgcn_global_load_lds( \
        (const __attribute__((address_space(1))) void*)(src), \
        (__attribute__((address_space(3))) void*)(dst), 16, 0, 0)

// ---------------------------------------------------------------------------
// Kernel 1: QKV projection.  (unchanged from round 5)
// ---------------------------------------------------------------------------
__global__ __launch_bounds__(256) void qkv_kernel(
    const float* __restrict__ x,
    const float* __restrict__ wq, const float* __restrict__ bq,
    const float* __restrict__ wk, const float* __restrict__ bk,
    const float* __restrict__ wv, const float* __restrict__ bv,
    unsigned short* __restrict__ qth, unsigned short* __restrict__ qtl,
    unsigned short* __restrict__ kth, unsigned short* __restrict__ ktl,
    unsigned short* __restrict__ vh)
{
    const int t0 = blockIdx.x * 64;
    const int ob = blockIdx.y;      // 0=q, 1=k, 2..9 = v row-blocks
    const int b  = blockIdx.z;

    const float* W; const float* bias; int orow0;
    if (ob == 0)      { W = wq; bias = bq; orow0 = 0; }
    else if (ob == 1) { W = wk; bias = bk; orow0 = 0; }
    else              { W = wv; bias = bv; orow0 = (ob - 2) * 64; }

    __shared__ float Xs[32][64];   // [cc][tt]
    __shared__ float Wt[32][68];   // [cc][oo]

    const int tid = threadIdx.x;
    const int tx = tid & 15;
    const int ty = tid >> 4;

    float acc[4][4];
    #pragma unroll
    for (int i = 0; i < 4; ++i)
        #pragma unroll
        for (int j = 0; j < 4; ++j) acc[i][j] = 0.f;

    const float* xb = x + (size_t)b * C_N * T_N;

    if (ob < 2) {
        for (int c0 = 0; c0 < C_N; c0 += 32) {
            {
                const int lt = tid & 63, lc = tid >> 6;
                #pragma unroll
                for (int r = 0; r < 8; ++r)
                    Xs[lc + r * 4][lt] = xb[(size_t)(c0 + lc + r * 4) * T_N + t0 + lt];
            }
            {
                const int lc = tid & 31, lo = tid >> 5;
                #pragma unroll
                for (int r = 0; r < 8; ++r)
                    Wt[lc][lo + r * 8] = W[(size_t)(orow0 + lo + r * 8) * C_N + c0 + lc];
            }
            __syncthreads();
            #pragma unroll
            for (int cc = 0; cc < 32; ++cc) {
                const float4 xv = *(const float4*)&Xs[cc][ty * 4];   // t part
                const float4 wv4 = *(const float4*)&Wt[cc][tx * 4];  // o part
                const float xv_[4] = {xv.x, xv.y, xv.z, xv.w};
                const float wv_[4] = {wv4.x, wv4.y, wv4.z, wv4.w};
                #pragma unroll
                for (int i = 0; i < 4; ++i)
                    #pragma unroll
                    for (int j = 0; j < 4; ++j)
                        acc[i][j] += xv_[i] * wv_[j];
            }
            __syncthreads();
        }
        unsigned short* dh = (ob == 0) ? qth : kth;
        unsigned short* dl = (ob == 0) ? qtl : ktl;
        const float4 b4 = *(const float4*)&bias[tx * 4];
        const float bb[4] = {b4.x, b4.y, b4.z, b4.w};
        #pragma unroll
        for (int i = 0; i < 4; ++i) {
            const int tt = ty * 4 + i;
            us4 h4, l4;
            #pragma unroll
            for (int j = 0; j < 4; ++j) {
                const float v = acc[i][j] + bb[j];
                const unsigned short hb = f2bf_bits(v);
                h4[j] = hb;
                l4[j] = f2bf_bits(v - bfbits2f(hb));
            }
            const size_t off = ((size_t)b * T_N + t0 + tt) * 64 + tx * 4;
            *(us4*)&dh[off] = h4;
            *(us4*)&dl[off] = l4;
        }
    } else {
        for (int c0 = 0; c0 < C_N; c0 += 32) {
            {
                const int lt = tid & 63, lc = tid >> 6;
                #pragma unroll
                for (int r = 0; r < 8; ++r)
                    Xs[lc + r * 4][lt] = xb[(size_t)(c0 + lc + r * 4) * T_N + t0 + lt];
            }
            {
                const int lc = tid & 31, lo = tid >> 5;
                #pragma unroll
                for (int r = 0; r < 8; ++r)
                    Wt[lc][lo + r * 8] = W[(size_t)(orow0 + lo + r * 8) * C_N + c0 + lc];
            }
            __syncthreads();
            #pragma unroll
            for (int cc = 0; cc < 32; ++cc) {
                const float4 xv = *(const float4*)&Xs[cc][tx * 4];   // t part
                const float4 wv4 = *(const float4*)&Wt[cc][ty * 4];  // o part
                const float xv_[4] = {xv.x, xv.y, xv.z, xv.w};
                const float wv_[4] = {wv4.x, wv4.y, wv4.z, wv4.w};
                #pragma unroll
                for (int i = 0; i < 4; ++i)
                    #pragma unroll
                    for (int j = 0; j < 4; ++j)
                        acc[i][j] += wv_[i] * xv_[j];
            }
            __syncthreads();
        }
        #pragma unroll
        for (int i = 0; i < 4; ++i) {
            const int oo = ty * 4 + i;
            const float bb = bias[orow0 + oo];
            us4 h4;
            #pragma unroll
            for (int j = 0; j < 4; ++j)
                h4[j] = f2bf_bits(acc[i][j] + bb);
            *(us4*)&vh[((size_t)b * C_N + orow0 + oo) * T_N + t0 + tx * 4] = h4;
        }
    }
}

// ---------------------------------------------------------------------------
// Kernel 2: MFMA flash attention, DMA-staged (global_load_lds) pipeline.
// Per s-tile: K(i+1) DMA rides the whole iteration (double-buffered LDS);
// V(i) DMA rides QK^T+softmax, drained by counted vmcnt(1). Raw s_barriers,
// no full vmcnt drains in the loop. Swizzles applied via source permutation
// (LDS dest linear per wave, read side uses same involution).
// ---------------------------------------------------------------------------
__global__ __launch_bounds__(512, 4) void attn_mfma_kernel(
    const float* __restrict__ x,
    const unsigned short* __restrict__ qth, const unsigned short* __restrict__ qtl,
    const unsigned short* __restrict__ kth, const unsigned short* __restrict__ ktl,
    const unsigned short* __restrict__ vh,
    const float* __restrict__ gamma,
    float* __restrict__ out)
{
    __shared__ unsigned short Qh_s[64 * 64];
    __shared__ unsigned short Ql_s[64 * 64];
    __shared__ unsigned short Kh_s[2][32 * 64];
    __shared__ unsigned short Kl_s[2][32 * 64];
    __shared__ unsigned short V_s[512 * 32];
    __shared__ unsigned short P_s[8 * 16 * 32];

    const int tid  = threadIdx.x;
    const int wave = tid >> 6;
    const int lane = tid & 63;
    const int ln   = lane & 15;
    const int lg   = lane >> 4;

    // XCD-aware remap (each XCD owns 2 complete batches)
    const int l    = blockIdx.x;
    const int slot = l >> 3;
    const int b    = ((l & 7) << 1) | (slot & 1);
    const int t0   = (slot >> 1) * 64;

    const int tb = wave & 3;        // t-block (16 rows)
    const int ch = wave >> 2;       // c-half  (256 cols)

    const unsigned short* kb_h = kth + (size_t)b * T_N * 64;
    const unsigned short* kb_l = ktl + (size_t)b * T_N * 64;
    const unsigned short* vb   = vh  + (size_t)b * C_N * T_N;

    // ---- DMA issue: K tile (hi+lo, 8KB) -> Kbuf[buf]; 1 call per wave.
    // LDS linear chunks; source pre-swizzled with KIDX's in-row involution.
    auto DMA_K = [&](int s0, int buf) {
        const int w4   = wave & 3;
        const int chnk = w4 * 64 + lane;          // 16B chunk within half-tile
        const int s    = chnk >> 3, jl = chnk & 7;
        const unsigned short* src =
            ((wave < 4) ? kb_h : kb_l) + (((size_t)(s0 + s)) << 6) + ((jl ^ (s & 7)) << 3);
        unsigned short* dst = ((wave < 4) ? &Kh_s[buf][0] : &Kl_s[buf][0]) + w4 * 512;
        GLD_LDS(src, dst);
    };
    // ---- DMA issue: V tile (32KB) -> V_s; 4 calls per wave.
    // Source pre-swizzled with VIDX2's in-row involution.
    auto DMA_V = [&](int s0) {
        #pragma unroll
        for (int q = 0; q < 4; ++q) {
            const int chnk = wave * 256 + q * 64 + lane;
            const int c = chnk >> 2, kl = chnk & 3;
            const int ks = kl ^ ((c >> 1) & 3);
            const unsigned short* src = vb + (size_t)c * T_N + s0 + ks * 8;
            unsigned short* dst = &V_s[0] + (wave * 256 + q * 64) * 8;
            GLD_LDS(src, dst);
        }
    };

    // ---- prologue: stage Q (regs->LDS), issue K(0) DMA
    {
        const int r = tid >> 3, c8 = (tid & 7) * 8;
        const size_t off = ((size_t)b * T_N + t0 + r) * 64 + c8;
        const int idx = QIDX(r, c8);
        *(us8*)&Qh_s[idx] = *(const us8*)&qth[off];
        *(us8*)&Ql_s[idx] = *(const us8*)&qtl[off];
    }
    DMA_K(0, 0);
    asm volatile("s_waitcnt lgkmcnt(0)" ::: "memory");
    __builtin_amdgcn_sched_barrier(0);

    const int trow = tb * 16 + ln;

    float m_run[4], l_run[4];
    #pragma unroll
    for (int r = 0; r < 4; ++r) { m_run[r] = -INFINITY; l_run[r] = 0.f; }

    f32x4 acc[16];
    #pragma unroll
    for (int ct = 0; ct < 16; ++ct) acc[ct] = (f32x4){0.f, 0.f, 0.f, 0.f};

    int p = 0;
    for (int it = 0; it < 64; ++it) {
        const int s0 = it * 32;

        // A: drain own K(it) (had a full PV phase to land), then barrier.
        asm volatile("s_waitcnt vmcnt(0)" ::: "memory");
        __builtin_amdgcn_sched_barrier(0);
        __builtin_amdgcn_s_barrier();
        __builtin_amdgcn_sched_barrier(0);

        // Issue V(it) (consumed this iter post-B) and K(it+1) (next iter).
        DMA_V(s0);
        const int nx = (it + 1 < 64 ? it + 1 : 63) * 32;
        DMA_K(nx, p ^ 1);

        // B: QK^T from Kbuf[p] + online softmax (V DMA in flight underneath)
        const unsigned short* khp = &Kh_s[p][0];
        const unsigned short* klp = &Kl_s[p][0];

        f32x4 S[2];
        S[0] = (f32x4){0.f, 0.f, 0.f, 0.f};
        S[1] = (f32x4){0.f, 0.f, 0.f, 0.f};
        #pragma unroll
        for (int kk = 0; kk < 2; ++kk) {
            const int d0 = kk * 32 + lg * 8;
            const bf16x8 ah = __builtin_bit_cast(bf16x8, *(const us8*)&Qh_s[QIDX(trow, d0)]);
            const bf16x8 al = __builtin_bit_cast(bf16x8, *(const us8*)&Ql_s[QIDX(trow, d0)]);
            #pragma unroll
            for (int st = 0; st < 2; ++st) {
                const int srow = st * 16 + ln;
                const bf16x8 bh = __builtin_bit_cast(bf16x8, *(const us8*)&khp[KIDX(srow, d0)]);
                const bf16x8 bl = __builtin_bit_cast(bf16x8, *(const us8*)&klp[KIDX(srow, d0)]);
                S[st] = mfma16(ah, bh, S[st]);
                S[st] = mfma16(ah, bl, S[st]);
                S[st] = mfma16(al, bh, S[st]);
            }
        }

        float rs[4];
        #pragma unroll
        for (int r = 0; r < 4; ++r) {
            float mx = fmaxf(S[0][r], S[1][r]);
            mx = fmaxf(mx, __shfl_xor(mx, 1));
            mx = fmaxf(mx, __shfl_xor(mx, 2));
            mx = fmaxf(mx, __shfl_xor(mx, 4));
            mx = fmaxf(mx, __shfl_xor(mx, 8));
            const float m_new = fmaxf(m_run[r], mx);
            const float rr = exp2f((m_run[r] - m_new) * LOG2E);
            const float p0 = exp2f((S[0][r] - m_new) * LOG2E);
            const float p1 = exp2f((S[1][r] - m_new) * LOG2E);
            float sm = p0 + p1;
            sm += __shfl_xor(sm, 1);
            sm += __shfl_xor(sm, 2);
            sm += __shfl_xor(sm, 4);
            sm += __shfl_xor(sm, 8);
            l_run[r] = l_run[r] * rr + sm;
            m_run[r] = m_new;
            rs[r] = rr;
            const int t = lg * 4 + r;
            P_s[wave * 512 + PIDX(t, ln)]      = f2bf_bits(p0);
            P_s[wave * 512 + PIDX(t, 16 + ln)] = f2bf_bits(p1);
        }

        #pragma unroll
        for (int ct = 0; ct < 16; ++ct)
            #pragma unroll
            for (int r = 0; r < 4; ++r) acc[ct][r] *= rs[r];

        // C: V(it) arrived (counted wait; K(it+1) stays in flight), publish.
        asm volatile("s_waitcnt vmcnt(1)" ::: "memory");
        __builtin_amdgcn_sched_barrier(0);
        __builtin_amdgcn_s_barrier();
        __builtin_amdgcn_sched_barrier(0);

        // D: PV
        const bf16x8 pa = __builtin_bit_cast(bf16x8,
            *(const us8*)&P_s[wave * 512 + PIDX(ln, lg * 8)]);
        #pragma unroll
        for (int ct = 0; ct < 16; ++ct) {
            const int c = ch * 256 + ct * 16 + ln;
            const bf16x8 bv = __builtin_bit_cast(bf16x8, *(const us8*)&V_s[VIDX2(c, lg * 8)]);
            acc[ct] = mfma16(pa, bv, acc[ct]);
        }
        p ^= 1;
    }

    // ---- epilogue: out = gamma * O / l + x
    const float g = gamma[0];
    float invl[4];
    #pragma unroll
    for (int r = 0; r < 4; ++r) invl[r] = 1.0f / l_run[r];

    const float* xb = x + (size_t)b * C_N * T_N;
    float* ob_ = out + (size_t)b * C_N * T_N;
    const int tl0 = t0 + tb * 16 + lg * 4;

    #pragma unroll
    for (int ct = 0; ct < 16; ++ct) {
        const int c = ch * 256 + ct * 16 + ln;
        const size_t off = (size_t)c * T_N + tl0;
        const float4 xv = *(const float4*)&xb[off];
        float4 o4;
        o4.x = g * acc[ct][0] * invl[0] + xv.x;
        o4.y = g * acc[ct][1] * invl[1] + xv.y;
        o4.z = g * acc[ct][2] * invl[2] + xv.z;
        o4.w = g * acc[ct][3] * invl[3] + xv.w;
        *(float4*)&ob_[off] = o4;
    }
}

// ---------------------------------------------------------------------------
extern "C" void kernel_launch(void* const* d_in, const int* in_sizes, int n_in,
                              void* d_out, int out_size, void* d_ws, size_t ws_size,
                              hipStream_t stream)
{
    const float* x     = (const float*)d_in[0];
    const float* wq    = (const float*)d_in[1];
    const float* bq    = (const float*)d_in[2];
    const float* wk    = (const float*)d_in[3];
    const float* bk    = (const float*)d_in[4];
    const float* wv    = (const float*)d_in[5];
    const float* bv    = (const float*)d_in[6];
    const float* gamma = (const float*)d_in[7];
    float* out = (float*)d_out;

    // ws layout (ushorts): qth | qtl | kth | ktl  [b][t][64] each, then v [b][c][T]
    unsigned short* qth = (unsigned short*)d_ws;
    unsigned short* qtl = qth + (size_t)B_N * T_N * 64;
    unsigned short* kth = qtl + (size_t)B_N * T_N * 64;
    unsigned short* ktl = kth + (size_t)B_N * T_N * 64;
    unsigned short* vh  = ktl + (size_t)B_N * T_N * 64;

    dim3 g1(T_N / 64, 10, B_N);
    qkv_kernel<<<g1, 256, 0, stream>>>(x, wq, bq, wk, bk, wv, bv,
                                       qth, qtl, kth, ktl, vh);

    attn_mfma_kernel<<<512, 512, 0, stream>>>(x, qth, qtl, kth, ktl, vh, gamma, out);

    (void)in_sizes; (void)n_in; (void)out_size; (void)ws_size;
}

// Round 9
// 465.215 us; speedup vs baseline: 3.2463x; 1.4062x over previous
//
#include <hip/hip_runtime.h>
#include <hip/hip_bf16.h>
#include <math.h>

#define B_N 16
#define C_N 512
#define T_N 2048
#define D_N 64
#define LOG2E 1.44269504088896340736f

typedef __attribute__((ext_vector_type(4))) float f32x4;
typedef __attribute__((ext_vector_type(8))) __bf16 bf16x8;
typedef __attribute__((ext_vector_type(8))) unsigned short us8;
typedef __attribute__((ext_vector_type(4))) unsigned short us4;

__device__ inline f32x4 mfma16(bf16x8 a, bf16x8 b, f32x4 c) {
    return __builtin_amdgcn_mfma_f32_16x16x32_bf16(a, b, c, 0, 0, 0);
}
__device__ inline unsigned short f2bf_bits(float v) {
    return __builtin_bit_cast(unsigned short, __float2bfloat16(v));
}
__device__ inline float bfbits2f(unsigned short u) {
    unsigned int x = ((unsigned int)u) << 16;
    return __builtin_bit_cast(float, x);
}

// swizzled LDS index helpers (ushort units)
#define QIDX(t,d) (((((t)<<6) | (d))) ^ ((((t)&7))<<3))
#define KIDX(s,d) (((((s)<<6) | (d))) ^ ((((s)&7))<<3))
#define VIDX2(c,s) (((c)<<5) | ((s) ^ (((((c)>>1))&3)<<3)))
#define PIDX(t,s) (((((t)<<5) | (s))) ^ ((((t)&7))<<3))

#define GLD_LDS(src, dst) \
    __builtin_amdgcn_global_load_lds( \
        (const __attribute__((address_space(1))) void*)(src), \
        (__attribute__((address_space(3))) void*)(dst), 16, 0, 0)

// ---------------------------------------------------------------------------
// Kernel 0: convert.  x f32 [b][c][t] -> xT bf16 [b][t][512] (LDS transpose);
// plus wq|wk|wv f32 -> whb bf16 (flat concat).
// ---------------------------------------------------------------------------
__global__ __launch_bounds__(256) void convert_kernel(
    const float* __restrict__ x,
    const float* __restrict__ wq, const float* __restrict__ wk,
    const float* __restrict__ wv,
    unsigned short* __restrict__ xt, unsigned short* __restrict__ whb)
{
    const int blk = blockIdx.x;
    const int tid = threadIdx.x;

    if (blk < 4096) {
        // x transpose: 64c x 64t tile
        const int b  = blk >> 8;
        const int rem = blk & 255;
        const int c0 = (rem >> 5) << 6;
        const int t0 = (rem & 31) << 6;

        __shared__ float Xs[64][65];
        const int lt = tid & 63, lc0 = tid >> 6;
        #pragma unroll
        for (int r = 0; r < 16; ++r)
            Xs[lc0 + r * 4][lt] =
                x[((size_t)b * C_N + c0 + lc0 + r * 4) * T_N + t0 + lt];
        __syncthreads();
        #pragma unroll
        for (int k = 0; k < 2; ++k) {
            const int j = tid + k * 256;
            const int tr = j >> 3, sg = j & 7;
            us8 v;
            #pragma unroll
            for (int e = 0; e < 8; ++e)
                v[e] = f2bf_bits(Xs[sg * 8 + e][tr]);
            *(us8*)&xt[((size_t)b * T_N + t0 + tr) * C_N + c0 + sg * 8] = v;
        }
    } else {
        // W convert: flat [wq|wk|wv], 8192 f32 per block
        const int wi = blk - 4096;
        #pragma unroll
        for (int q = 0; q < 8; ++q) {
            const int idx4 = wi * 8192 + q * 1024 + tid * 4;
            const float* s; int off;
            if (idx4 < 32768)      { s = wq; off = idx4; }
            else if (idx4 < 65536) { s = wk; off = idx4 - 32768; }
            else                   { s = wv; off = idx4 - 65536; }
            const float4 v4 = *(const float4*)&s[off];
            us4 h;
            h[0] = f2bf_bits(v4.x); h[1] = f2bf_bits(v4.y);
            h[2] = f2bf_bits(v4.z); h[3] = f2bf_bits(v4.w);
            *(us4*)&whb[idx4] = h;
        }
    }
}

// ---------------------------------------------------------------------------
// Kernel 1: QKV projection via MFMA.
// Block = 64 out-rows x 128 t, K=512 in 8 chunks of 64, DMA-staged.
// Grid 2560 = 16b x 16tt x 10ob, swizzled so a (b,tt) pair's 10 ob-blocks
// share one XCD (xT tile L2 reuse).
// Epilogue through LDS for coalesced stores; q,k emitted as hi/lo bf16 pair.
// ---------------------------------------------------------------------------
__global__ __launch_bounds__(512, 3) void qkv_mfma_kernel(
    const unsigned short* __restrict__ xt, const unsigned short* __restrict__ whb,
    const float* __restrict__ bq, const float* __restrict__ bk,
    const float* __restrict__ bv,
    unsigned short* __restrict__ qth, unsigned short* __restrict__ qtl,
    unsigned short* __restrict__ kth, unsigned short* __restrict__ ktl,
    unsigned short* __restrict__ vh)
{
    __shared__ unsigned short XTs[2][8192];   // [128 t][64 c] swizzled
    __shared__ unsigned short Ws[2][4096];    // [64 o][64 c] swizzled

    const int tid  = threadIdx.x;
    const int wave = tid >> 6;
    const int lane = tid & 63;
    const int ln   = lane & 15;
    const int lg   = lane >> 4;

    // inverse grid swizzle: l = (pair&7) | ((ph*10+ob)<<3), pair = ph*8+(l&7)
    const int l    = blockIdx.x;
    const int low3 = l & 7;
    const int rest = l >> 3;
    const int ob   = rest % 10;
    const int ph   = rest / 10;
    const int pair = (ph << 3) | low3;
    const int b    = pair >> 4;
    const int t0   = (pair & 15) << 7;    // 128-t tile

    const unsigned short* wbase; const float* bias; int orow0;
    if (ob == 0)      { wbase = whb;          bias = bq; orow0 = 0; }
    else if (ob == 1) { wbase = whb + 32768;  bias = bk; orow0 = 0; }
    else              { wbase = whb + 65536;  bias = bv; orow0 = (ob - 2) * 64; }

    const unsigned short* xb = xt + (size_t)b * T_N * C_N;

    const int wo = wave & 3;   // o 16-row group
    const int wt = wave >> 2;  // t 64-col half

    // DMA: xT chunk [128t][64c] (2/thread) + W chunk [64o][64c] (1/thread)
    auto DMA = [&](int it, int buf) {
        const int c0 = it * 64;
        #pragma unroll
        for (int k = 0; k < 2; ++k) {
            const int j = tid + k * 512;
            const int t = j >> 3, cs = j & 7;
            const unsigned short* src =
                xb + (size_t)(t0 + t) * C_N + c0 + ((cs ^ (t & 7)) << 3);
            GLD_LDS(src, &XTs[buf][j * 8]);
        }
        {
            const int o = tid >> 3, cs = tid & 7;
            const unsigned short* src =
                wbase + (size_t)(orow0 + o) * C_N + c0 + ((cs ^ (o & 7)) << 3);
            if (tid < 512) GLD_LDS(src, &Ws[buf][tid * 8]);
        }
    };

    f32x4 acc[4];
    #pragma unroll
    for (int st = 0; st < 4; ++st) acc[st] = (f32x4){0.f, 0.f, 0.f, 0.f};

    DMA(0, 0);

    int p = 0;
    for (int it = 0; it < 8; ++it) {
        asm volatile("s_waitcnt vmcnt(0)" ::: "memory");
        __builtin_amdgcn_sched_barrier(0);
        __builtin_amdgcn_s_barrier();
        __builtin_amdgcn_sched_barrier(0);

        if (it < 7) DMA(it + 1, p ^ 1);

        #pragma unroll
        for (int kk = 0; kk < 2; ++kk) {
            const int co = kk * 32 + lg * 8;
            const bf16x8 ah = __builtin_bit_cast(bf16x8,
                *(const us8*)&Ws[p][(((wo * 16 + ln) << 6) | co) ^ ((ln & 7) << 3)]);
            #pragma unroll
            for (int st = 0; st < 4; ++st) {
                const int t = wt * 64 + st * 16 + ln;
                const bf16x8 bv8 = __builtin_bit_cast(bf16x8,
                    *(const us8*)&XTs[p][((t << 6) | co) ^ ((ln & 7) << 3)]);
                acc[st] = mfma16(ah, bv8, acc[st]);
            }
        }
        p ^= 1;
    }

    __syncthreads();   // all MFMA reads done; reuse XTs as epilogue buffer

    // bias add (o = wo*16 + lg*4 + r)
    float bb[4];
    #pragma unroll
    for (int r = 0; r < 4; ++r) bb[r] = bias[orow0 + wo * 16 + lg * 4 + r];

    unsigned short* ep0 = &XTs[0][0];
    unsigned short* ep1 = &XTs[1][0];

    if (ob < 2) {
        // Ep [128 t][64 o] hi/lo, swizzled; then coalesced us8 stores
        #pragma unroll
        for (int st = 0; st < 4; ++st) {
            const int t = wt * 64 + st * 16 + ln;
            #pragma unroll
            for (int r = 0; r < 4; ++r) {
                const float v = acc[st][r] + bb[r];
                const int o = wo * 16 + lg * 4 + r;
                const int idx = ((t << 6) | o) ^ ((t & 7) << 3);
                const unsigned short hb = f2bf_bits(v);
                ep0[idx] = hb;
                ep1[idx] = f2bf_bits(v - bfbits2f(hb));
            }
        }
        __syncthreads();
        unsigned short* dh = (ob == 0) ? qth : kth;
        unsigned short* dl = (ob == 0) ? qtl : ktl;
        #pragma unroll
        for (int k = 0; k < 2; ++k) {
            const int j = tid + k * 512;
            const int t = j >> 3, sg = j & 7;
            const int idx = (t << 6) | ((sg ^ (t & 7)) << 3);
            const size_t off = ((size_t)b * T_N + t0 + t) * 64 + sg * 8;
            *(us8*)&dh[off] = *(const us8*)&ep0[idx];
            *(us8*)&dl[off] = *(const us8*)&ep1[idx];
        }
    } else {
        // Ep [64 o][128 t] bf16, swizzled; coalesced us8 stores to vh [b][c][t]
        #pragma unroll
        for (int st = 0; st < 4; ++st) {
            const int t = wt * 64 + st * 16 + ln;
            #pragma unroll
            for (int r = 0; r < 4; ++r) {
                const int o = wo * 16 + lg * 4 + r;
                const int idx = ((o << 7) | t) ^ ((o & 7) << 3);
                ep0[idx] = f2bf_bits(acc[st][r] + bb[r]);
            }
        }
        __syncthreads();
        #pragma unroll
        for (int k = 0; k < 2; ++k) {
            const int j = tid + k * 512;
            const int o = j >> 4, sg = j & 15;
            const int idx = ((o << 7) | (sg << 3)) ^ ((o & 7) << 3);
            const size_t off = ((size_t)b * C_N + orow0 + o) * T_N + t0 + sg * 8;
            *(us8*)&vh[off] = *(const us8*)&ep0[idx];
        }
    }
}

// ---------------------------------------------------------------------------
// Kernel 2: MFMA flash attention (unchanged from round 7).
// ---------------------------------------------------------------------------
__global__ __launch_bounds__(512, 4) void attn_mfma_kernel(
    const float* __restrict__ x,
    const unsigned short* __restrict__ qth, const unsigned short* __restrict__ qtl,
    const unsigned short* __restrict__ kth, const unsigned short* __restrict__ ktl,
    const unsigned short* __restrict__ vh,
    const float* __restrict__ gamma,
    float* __restrict__ out)
{
    __shared__ unsigned short Qh_s[64 * 64];
    __shared__ unsigned short Ql_s[64 * 64];
    __shared__ unsigned short Kh_s[2][32 * 64];
    __shared__ unsigned short Kl_s[2][32 * 64];
    __shared__ unsigned short V_s[512 * 32];
    __shared__ unsigned short P_s[8 * 16 * 32];

    const int tid  = threadIdx.x;
    const int wave = tid >> 6;
    const int lane = tid & 63;
    const int ln   = lane & 15;
    const int lg   = lane >> 4;

    const int l    = blockIdx.x;
    const int slot = l >> 3;
    const int b    = ((l & 7) << 1) | (slot & 1);
    const int t0   = (slot >> 1) * 64;

    const int tb = wave & 3;
    const int ch = wave >> 2;

    const unsigned short* kb_h = kth + (size_t)b * T_N * 64;
    const unsigned short* kb_l = ktl + (size_t)b * T_N * 64;
    const unsigned short* vb   = vh  + (size_t)b * C_N * T_N;

    auto DMA_K = [&](int s0, int buf) {
        const int w4   = wave & 3;
        const int chnk = w4 * 64 + lane;
        const int s    = chnk >> 3, jl = chnk & 7;
        const unsigned short* src =
            ((wave < 4) ? kb_h : kb_l) + (((size_t)(s0 + s)) << 6) + ((jl ^ (s & 7)) << 3);
        unsigned short* dst = ((wave < 4) ? &Kh_s[buf][0] : &Kl_s[buf][0]) + w4 * 512;
        GLD_LDS(src, dst);
    };
    auto DMA_V = [&](int s0) {
        #pragma unroll
        for (int q = 0; q < 4; ++q) {
            const int chnk = wave * 256 + q * 64 + lane;
            const int c = chnk >> 2, kl = chnk & 3;
            const int ks = kl ^ ((c >> 1) & 3);
            const unsigned short* src = vb + (size_t)c * T_N + s0 + ks * 8;
            unsigned short* dst = &V_s[0] + (wave * 256 + q * 64) * 8;
            GLD_LDS(src, dst);
        }
    };

    {
        const int r = tid >> 3, c8 = (tid & 7) * 8;
        const size_t off = ((size_t)b * T_N + t0 + r) * 64 + c8;
        const int idx = QIDX(r, c8);
        *(us8*)&Qh_s[idx] = *(const us8*)&qth[off];
        *(us8*)&Ql_s[idx] = *(const us8*)&qtl[off];
    }
    DMA_K(0, 0);
    asm volatile("s_waitcnt lgkmcnt(0)" ::: "memory");
    __builtin_amdgcn_sched_barrier(0);

    const int trow = tb * 16 + ln;

    float m_run[4], l_run[4];
    #pragma unroll
    for (int r = 0; r < 4; ++r) { m_run[r] = -INFINITY; l_run[r] = 0.f; }

    f32x4 acc[16];
    #pragma unroll
    for (int ct = 0; ct < 16; ++ct) acc[ct] = (f32x4){0.f, 0.f, 0.f, 0.f};

    int p = 0;
    for (int it = 0; it < 64; ++it) {
        const int s0 = it * 32;

        asm volatile("s_waitcnt vmcnt(0)" ::: "memory");
        __builtin_amdgcn_sched_barrier(0);
        __builtin_amdgcn_s_barrier();
        __builtin_amdgcn_sched_barrier(0);

        DMA_V(s0);
        const int nx = (it + 1 < 64 ? it + 1 : 63) * 32;
        DMA_K(nx, p ^ 1);

        const unsigned short* khp = &Kh_s[p][0];
        const unsigned short* klp = &Kl_s[p][0];

        f32x4 S[2];
        S[0] = (f32x4){0.f, 0.f, 0.f, 0.f};
        S[1] = (f32x4){0.f, 0.f, 0.f, 0.f};
        #pragma unroll
        for (int kk = 0; kk < 2; ++kk) {
            const int d0 = kk * 32 + lg * 8;
            const bf16x8 ah = __builtin_bit_cast(bf16x8, *(const us8*)&Qh_s[QIDX(trow, d0)]);
            const bf16x8 al = __builtin_bit_cast(bf16x8, *(const us8*)&Ql_s[QIDX(trow, d0)]);
            #pragma unroll
            for (int st = 0; st < 2; ++st) {
                const int srow = st * 16 + ln;
                const bf16x8 bh = __builtin_bit_cast(bf16x8, *(const us8*)&khp[KIDX(srow, d0)]);
                const bf16x8 bl = __builtin_bit_cast(bf16x8, *(const us8*)&klp[KIDX(srow, d0)]);
                S[st] = mfma16(ah, bh, S[st]);
                S[st] = mfma16(ah, bl, S[st]);
                S[st] = mfma16(al, bh, S[st]);
            }
        }

        float rs[4];
        #pragma unroll
        for (int r = 0; r < 4; ++r) {
            float mx = fmaxf(S[0][r], S[1][r]);
            mx = fmaxf(mx, __shfl_xor(mx, 1));
            mx = fmaxf(mx, __shfl_xor(mx, 2));
            mx = fmaxf(mx, __shfl_xor(mx, 4));
            mx = fmaxf(mx, __shfl_xor(mx, 8));
            const float m_new = fmaxf(m_run[r], mx);
            const float rr = exp2f((m_run[r] - m_new) * LOG2E);
            const float p0 = exp2f((S[0][r] - m_new) * LOG2E);
            const float p1 = exp2f((S[1][r] - m_new) * LOG2E);
            float sm = p0 + p1;
            sm += __shfl_xor(sm, 1);
            sm += __shfl_xor(sm, 2);
            sm += __shfl_xor(sm, 4);
            sm += __shfl_xor(sm, 8);
            l_run[r] = l_run[r] * rr + sm;
            m_run[r] = m_new;
            rs[r] = rr;
            const int t = lg * 4 + r;
            P_s[wave * 512 + PIDX(t, ln)]      = f2bf_bits(p0);
            P_s[wave * 512 + PIDX(t, 16 + ln)] = f2bf_bits(p1);
        }

        #pragma unroll
        for (int ct = 0; ct < 16; ++ct)
            #pragma unroll
            for (int r = 0; r < 4; ++r) acc[ct][r] *= rs[r];

        asm volatile("s_waitcnt vmcnt(1)" ::: "memory");
        __builtin_amdgcn_sched_barrier(0);
        __builtin_amdgcn_s_barrier();
        __builtin_amdgcn_sched_barrier(0);

        const bf16x8 pa = __builtin_bit_cast(bf16x8,
            *(const us8*)&P_s[wave * 512 + PIDX(ln, lg * 8)]);
        #pragma unroll
        for (int ct = 0; ct < 16; ++ct) {
            const int c = ch * 256 + ct * 16 + ln;
            const bf16x8 bv = __builtin_bit_cast(bf16x8, *(const us8*)&V_s[VIDX2(c, lg * 8)]);
            acc[ct] = mfma16(pa, bv, acc[ct]);
        }
        p ^= 1;
    }

    const float g = gamma[0];
    float invl[4];
    #pragma unroll
    for (int r = 0; r < 4; ++r) invl[r] = 1.0f / l_run[r];

    const float* xb = x + (size_t)b * C_N * T_N;
    float* ob_ = out + (size_t)b * C_N * T_N;
    const int tl0 = t0 + tb * 16 + lg * 4;

    #pragma unroll
    for (int ct = 0; ct < 16; ++ct) {
        const int c = ch * 256 + ct * 16 + ln;
        const size_t off = (size_t)c * T_N + tl0;
        const float4 xv = *(const float4*)&xb[off];
        float4 o4;
        o4.x = g * acc[ct][0] * invl[0] + xv.x;
        o4.y = g * acc[ct][1] * invl[1] + xv.y;
        o4.z = g * acc[ct][2] * invl[2] + xv.z;
        o4.w = g * acc[ct][3] * invl[3] + xv.w;
        *(float4*)&ob_[off] = o4;
    }
}

// ---------------------------------------------------------------------------
extern "C" void kernel_launch(void* const* d_in, const int* in_sizes, int n_in,
                              void* d_out, int out_size, void* d_ws, size_t ws_size,
                              hipStream_t stream)
{
    const float* x     = (const float*)d_in[0];
    const float* wq    = (const float*)d_in[1];
    const float* bq    = (const float*)d_in[2];
    const float* wk    = (const float*)d_in[3];
    const float* bk    = (const float*)d_in[4];
    const float* wv    = (const float*)d_in[5];
    const float* bv    = (const float*)d_in[6];
    const float* gamma = (const float*)d_in[7];
    float* out = (float*)d_out;

    // ws (ushorts): qth|qtl|kth|ktl [b][t][64] | vh [b][c][t] | xt [b][t][512] | whb
    unsigned short* qth = (unsigned short*)d_ws;
    unsigned short* qtl = qth + (size_t)B_N * T_N * 64;
    unsigned short* kth = qtl + (size_t)B_N * T_N * 64;
    unsigned short* ktl = kth + (size_t)B_N * T_N * 64;
    unsigned short* vh  = ktl + (size_t)B_N * T_N * 64;
    unsigned short* xt  = vh  + (size_t)B_N * C_N * T_N;
    unsigned short* whb = xt  + (size_t)B_N * T_N * C_N;

    convert_kernel<<<4136, 256, 0, stream>>>(x, wq, wk, wv, xt, whb);

    qkv_mfma_kernel<<<2560, 512, 0, stream>>>(xt, whb, bq, bk, bv,
                                              qth, qtl, kth, ktl, vh);

    attn_mfma_kernel<<<512, 512, 0, stream>>>(x, qth, qtl, kth, ktl, vh, gamma, out);

    (void)in_sizes; (void)n_in; (void)out_size; (void)ws_size;
}

// Round 10
// 443.259 us; speedup vs baseline: 3.4071x; 1.0495x over previous
//
#include <hip/hip_runtime.h>
#include <hip/hip_bf16.h>
#include <math.h>

#define B_N 16
#define C_N 512
#define T_N 2048
#define D_N 64
#define LOG2E 1.44269504088896340736f

typedef __attribute__((ext_vector_type(4))) float f32x4;
typedef __attribute__((ext_vector_type(16))) float f32x16;
typedef __attribute__((ext_vector_type(8))) __bf16 bf16x8;
typedef __attribute__((ext_vector_type(8))) unsigned short us8;
typedef __attribute__((ext_vector_type(4))) unsigned short us4;

__device__ inline f32x4 mfma16(bf16x8 a, bf16x8 b, f32x4 c) {
    return __builtin_amdgcn_mfma_f32_16x16x32_bf16(a, b, c, 0, 0, 0);
}
__device__ inline f32x16 mfma32(bf16x8 a, bf16x8 b, f32x16 c) {
    return __builtin_amdgcn_mfma_f32_32x32x16_bf16(a, b, c, 0, 0, 0);
}
__device__ inline unsigned short f2bf_bits(float v) {
    return __builtin_bit_cast(unsigned short, __float2bfloat16(v));
}
__device__ inline float bfbits2f(unsigned short u) {
    unsigned int x = ((unsigned int)u) << 16;
    return __builtin_bit_cast(float, x);
}

// swizzled LDS index helpers (ushort units)
#define QIDX(t,d) (((((t)<<6) | (d))) ^ ((((t)&7))<<3))
#define KIDX(s,d) (((((s)<<6) | (d))) ^ ((((s)&7))<<3))
#define VIDX2(c,s) (((c)<<5) | ((s) ^ (((((c)>>1))&3)<<3)))
#define PIDX(t,s) (((((t)<<5) | (s))) ^ ((((t)&7))<<3))

#define GLD_LDS(src, dst) \
    __builtin_amdgcn_global_load_lds( \
        (const __attribute__((address_space(1))) void*)(src), \
        (__attribute__((address_space(3))) void*)(dst), 16, 0, 0)

// ---------------------------------------------------------------------------
// Kernel 0: convert (unchanged from round 9).
// ---------------------------------------------------------------------------
__global__ __launch_bounds__(256) void convert_kernel(
    const float* __restrict__ x,
    const float* __restrict__ wq, const float* __restrict__ wk,
    const float* __restrict__ wv,
    unsigned short* __restrict__ xt, unsigned short* __restrict__ whb)
{
    const int blk = blockIdx.x;
    const int tid = threadIdx.x;

    if (blk < 4096) {
        const int b  = blk >> 8;
        const int rem = blk & 255;
        const int c0 = (rem >> 5) << 6;
        const int t0 = (rem & 31) << 6;

        __shared__ float Xs[64][65];
        const int lt = tid & 63, lc0 = tid >> 6;
        #pragma unroll
        for (int r = 0; r < 16; ++r)
            Xs[lc0 + r * 4][lt] =
                x[((size_t)b * C_N + c0 + lc0 + r * 4) * T_N + t0 + lt];
        __syncthreads();
        #pragma unroll
        for (int k = 0; k < 2; ++k) {
            const int j = tid + k * 256;
            const int tr = j >> 3, sg = j & 7;
            us8 v;
            #pragma unroll
            for (int e = 0; e < 8; ++e)
                v[e] = f2bf_bits(Xs[sg * 8 + e][tr]);
            *(us8*)&xt[((size_t)b * T_N + t0 + tr) * C_N + c0 + sg * 8] = v;
        }
    } else {
        const int wi = blk - 4096;
        #pragma unroll
        for (int q = 0; q < 8; ++q) {
            const int idx4 = wi * 8192 + q * 1024 + tid * 4;
            const float* s; int off;
            if (idx4 < 32768)      { s = wq; off = idx4; }
            else if (idx4 < 65536) { s = wk; off = idx4 - 32768; }
            else                   { s = wv; off = idx4 - 65536; }
            const float4 v4 = *(const float4*)&s[off];
            us4 h;
            h[0] = f2bf_bits(v4.x); h[1] = f2bf_bits(v4.y);
            h[2] = f2bf_bits(v4.z); h[3] = f2bf_bits(v4.w);
            *(us4*)&whb[idx4] = h;
        }
    }
}

// ---------------------------------------------------------------------------
// Kernel 1: QKV projection via MFMA (unchanged from round 9).
// ---------------------------------------------------------------------------
__global__ __launch_bounds__(512, 3) void qkv_mfma_kernel(
    const unsigned short* __restrict__ xt, const unsigned short* __restrict__ whb,
    const float* __restrict__ bq, const float* __restrict__ bk,
    const float* __restrict__ bv,
    unsigned short* __restrict__ qth, unsigned short* __restrict__ qtl,
    unsigned short* __restrict__ kth, unsigned short* __restrict__ ktl,
    unsigned short* __restrict__ vh)
{
    __shared__ unsigned short XTs[2][8192];
    __shared__ unsigned short Ws[2][4096];

    const int tid  = threadIdx.x;
    const int wave = tid >> 6;
    const int lane = tid & 63;
    const int ln   = lane & 15;
    const int lg   = lane >> 4;

    const int l    = blockIdx.x;
    const int low3 = l & 7;
    const int rest = l >> 3;
    const int ob   = rest % 10;
    const int ph   = rest / 10;
    const int pair = (ph << 3) | low3;
    const int b    = pair >> 4;
    const int t0   = (pair & 15) << 7;

    const unsigned short* wbase; const float* bias; int orow0;
    if (ob == 0)      { wbase = whb;          bias = bq; orow0 = 0; }
    else if (ob == 1) { wbase = whb + 32768;  bias = bk; orow0 = 0; }
    else              { wbase = whb + 65536;  bias = bv; orow0 = (ob - 2) * 64; }

    const unsigned short* xb = xt + (size_t)b * T_N * C_N;

    const int wo = wave & 3;
    const int wt = wave >> 2;

    auto DMA = [&](int it, int buf) {
        const int c0 = it * 64;
        #pragma unroll
        for (int k = 0; k < 2; ++k) {
            const int j = tid + k * 512;
            const int t = j >> 3, cs = j & 7;
            const unsigned short* src =
                xb + (size_t)(t0 + t) * C_N + c0 + ((cs ^ (t & 7)) << 3);
            GLD_LDS(src, &XTs[buf][j * 8]);
        }
        {
            const int o = tid >> 3, cs = tid & 7;
            const unsigned short* src =
                wbase + (size_t)(orow0 + o) * C_N + c0 + ((cs ^ (o & 7)) << 3);
            if (tid < 512) GLD_LDS(src, &Ws[buf][tid * 8]);
        }
    };

    f32x4 acc[4];
    #pragma unroll
    for (int st = 0; st < 4; ++st) acc[st] = (f32x4){0.f, 0.f, 0.f, 0.f};

    DMA(0, 0);

    int p = 0;
    for (int it = 0; it < 8; ++it) {
        asm volatile("s_waitcnt vmcnt(0)" ::: "memory");
        __builtin_amdgcn_sched_barrier(0);
        __builtin_amdgcn_s_barrier();
        __builtin_amdgcn_sched_barrier(0);

        if (it < 7) DMA(it + 1, p ^ 1);

        #pragma unroll
        for (int kk = 0; kk < 2; ++kk) {
            const int co = kk * 32 + lg * 8;
            const bf16x8 ah = __builtin_bit_cast(bf16x8,
                *(const us8*)&Ws[p][(((wo * 16 + ln) << 6) | co) ^ ((ln & 7) << 3)]);
            #pragma unroll
            for (int st = 0; st < 4; ++st) {
                const int t = wt * 64 + st * 16 + ln;
                const bf16x8 bv8 = __builtin_bit_cast(bf16x8,
                    *(const us8*)&XTs[p][((t << 6) | co) ^ ((ln & 7) << 3)]);
                acc[st] = mfma16(ah, bv8, acc[st]);
            }
        }
        p ^= 1;
    }

    __syncthreads();

    float bb[4];
    #pragma unroll
    for (int r = 0; r < 4; ++r) bb[r] = bias[orow0 + wo * 16 + lg * 4 + r];

    unsigned short* ep0 = &XTs[0][0];
    unsigned short* ep1 = &XTs[1][0];

    if (ob < 2) {
        #pragma unroll
        for (int st = 0; st < 4; ++st) {
            const int t = wt * 64 + st * 16 + ln;
            #pragma unroll
            for (int r = 0; r < 4; ++r) {
                const float v = acc[st][r] + bb[r];
                const int o = wo * 16 + lg * 4 + r;
                const int idx = ((t << 6) | o) ^ ((t & 7) << 3);
                const unsigned short hb = f2bf_bits(v);
                ep0[idx] = hb;
                ep1[idx] = f2bf_bits(v - bfbits2f(hb));
            }
        }
        __syncthreads();
        unsigned short* dh = (ob == 0) ? qth : kth;
        unsigned short* dl = (ob == 0) ? qtl : ktl;
        #pragma unroll
        for (int k = 0; k < 2; ++k) {
            const int j = tid + k * 512;
            const int t = j >> 3, sg = j & 7;
            const int idx = (t << 6) | ((sg ^ (t & 7)) << 3);
            const size_t off = ((size_t)b * T_N + t0 + t) * 64 + sg * 8;
            *(us8*)&dh[off] = *(const us8*)&ep0[idx];
            *(us8*)&dl[off] = *(const us8*)&ep1[idx];
        }
    } else {
        #pragma unroll
        for (int st = 0; st < 4; ++st) {
            const int t = wt * 64 + st * 16 + ln;
            #pragma unroll
            for (int r = 0; r < 4; ++r) {
                const int o = wo * 16 + lg * 4 + r;
                const int idx = ((o << 7) | t) ^ ((o & 7) << 3);
                ep0[idx] = f2bf_bits(acc[st][r] + bb[r]);
            }
        }
        __syncthreads();
        #pragma unroll
        for (int k = 0; k < 2; ++k) {
            const int j = tid + k * 512;
            const int o = j >> 4, sg = j & 15;
            const int idx = ((o << 7) | (sg << 3)) ^ ((o & 7) << 3);
            const size_t off = ((size_t)b * C_N + orow0 + o) * T_N + t0 + sg * 8;
            *(us8*)&vh[off] = *(const us8*)&ep0[idx];
        }
    }
}

// ---------------------------------------------------------------------------
// Kernel 2: MFMA flash attention, v2.
// QK^T+softmax on waves 0-3 only (shared via P2/r_lds/nflag — the ch-duplicate
// is eliminated). PV on all 8 waves via 32x32x16 MFMAs, wave = (t-half,
// c-quarter): V LDS reads halved. Defer-max (THR=8) gates the acc rescale.
// ---------------------------------------------------------------------------
__global__ __launch_bounds__(512, 4) void attn_mfma_kernel(
    const float* __restrict__ x,
    const unsigned short* __restrict__ qth, const unsigned short* __restrict__ qtl,
    const unsigned short* __restrict__ kth, const unsigned short* __restrict__ ktl,
    const unsigned short* __restrict__ vh,
    const float* __restrict__ gamma,
    float* __restrict__ out)
{
    __shared__ unsigned short Qh_s[64 * 64];
    __shared__ unsigned short Ql_s[64 * 64];
    __shared__ unsigned short Kh_s[2][32 * 64];
    __shared__ unsigned short Kl_s[2][32 * 64];
    __shared__ unsigned short V_s[512 * 32];
    __shared__ unsigned short P2[64 * 32];
    __shared__ float r_lds[64];
    __shared__ float l_lds[64];
    __shared__ unsigned nflag[4];

    const int tid  = threadIdx.x;
    const int wave = tid >> 6;
    const int lane = tid & 63;
    const int ln   = lane & 15;
    const int lg   = lane >> 4;
    const int hi   = lane >> 5;      // 32-lane half
    const int l31  = lane & 31;

    // XCD-aware remap (each XCD owns 2 complete batches)
    const int l    = blockIdx.x;
    const int slot = l >> 3;
    const int b    = ((l & 7) << 1) | (slot & 1);
    const int t0   = (slot >> 1) * 64;

    const int tb = wave & 3;        // softmax t-block (waves 0-3)
    const int tq = wave & 1;        // PV t-half
    const int cq = wave >> 1;       // PV c-quarter

    const unsigned short* kb_h = kth + (size_t)b * T_N * 64;
    const unsigned short* kb_l = ktl + (size_t)b * T_N * 64;
    const unsigned short* vb   = vh  + (size_t)b * C_N * T_N;

    auto DMA_K = [&](int s0, int buf) {
        const int w4   = wave & 3;
        const int chnk = w4 * 64 + lane;
        const int s    = chnk >> 3, jl = chnk & 7;
        const unsigned short* src =
            ((wave < 4) ? kb_h : kb_l) + (((size_t)(s0 + s)) << 6) + ((jl ^ (s & 7)) << 3);
        unsigned short* dst = ((wave < 4) ? &Kh_s[buf][0] : &Kl_s[buf][0]) + w4 * 512;
        GLD_LDS(src, dst);
    };
    auto DMA_V = [&](int s0) {
        #pragma unroll
        for (int q = 0; q < 4; ++q) {
            const int chnk = wave * 256 + q * 64 + lane;
            const int c = chnk >> 2, kl = chnk & 3;
            const int ks = kl ^ ((c >> 1) & 3);
            const unsigned short* src = vb + (size_t)c * T_N + s0 + ks * 8;
            unsigned short* dst = &V_s[0] + (wave * 256 + q * 64) * 8;
            GLD_LDS(src, dst);
        }
    };

    // prologue: stage Q, issue K(0)
    {
        const int r = tid >> 3, c8 = (tid & 7) * 8;
        const size_t off = ((size_t)b * T_N + t0 + r) * 64 + c8;
        const int idx = QIDX(r, c8);
        *(us8*)&Qh_s[idx] = *(const us8*)&qth[off];
        *(us8*)&Ql_s[idx] = *(const us8*)&qtl[off];
    }
    DMA_K(0, 0);
    asm volatile("s_waitcnt lgkmcnt(0)" ::: "memory");
    __builtin_amdgcn_sched_barrier(0);

    const int trow = tb * 16 + ln;

    float m_run[4], l_run[4];
    #pragma unroll
    for (int r = 0; r < 4; ++r) { m_run[r] = -INFINITY; l_run[r] = 0.f; }

    f32x16 acc32[4];
    #pragma unroll
    for (int ci = 0; ci < 4; ++ci)
        #pragma unroll
        for (int j = 0; j < 16; ++j) acc32[ci][j] = 0.f;

    int p = 0;
    for (int it = 0; it < 64; ++it) {
        const int s0 = it * 32;

        // A: own K(it) landed (rode the whole prev iter), publish V/K buffers.
        asm volatile("s_waitcnt vmcnt(0)" ::: "memory");
        __builtin_amdgcn_sched_barrier(0);
        __builtin_amdgcn_s_barrier();
        __builtin_amdgcn_sched_barrier(0);

        DMA_V(s0);
        const int nx = (it + 1 < 64 ? it + 1 : 63) * 32;
        DMA_K(nx, p ^ 1);

        if (wave < 4) {
            // ---- QK^T (waves 0-3 only; ch-duplication removed)
            const unsigned short* khp = &Kh_s[p][0];
            const unsigned short* klp = &Kl_s[p][0];

            f32x4 S[2];
            S[0] = (f32x4){0.f, 0.f, 0.f, 0.f};
            S[1] = (f32x4){0.f, 0.f, 0.f, 0.f};
            __builtin_amdgcn_s_setprio(1);
            #pragma unroll
            for (int kk = 0; kk < 2; ++kk) {
                const int d0 = kk * 32 + lg * 8;
                const bf16x8 ah = __builtin_bit_cast(bf16x8, *(const us8*)&Qh_s[QIDX(trow, d0)]);
                const bf16x8 al = __builtin_bit_cast(bf16x8, *(const us8*)&Ql_s[QIDX(trow, d0)]);
                #pragma unroll
                for (int st = 0; st < 2; ++st) {
                    const int srow = st * 16 + ln;
                    const bf16x8 bh = __builtin_bit_cast(bf16x8, *(const us8*)&khp[KIDX(srow, d0)]);
                    const bf16x8 bl = __builtin_bit_cast(bf16x8, *(const us8*)&klp[KIDX(srow, d0)]);
                    S[st] = mfma16(ah, bh, S[st]);
                    S[st] = mfma16(ah, bl, S[st]);
                    S[st] = mfma16(al, bh, S[st]);
                }
            }
            __builtin_amdgcn_s_setprio(0);

            // ---- online softmax with defer-max (THR=8)
            float mx[4];
            #pragma unroll
            for (int r = 0; r < 4; ++r) {
                float m = fmaxf(S[0][r], S[1][r]);
                m = fmaxf(m, __shfl_xor(m, 1));
                m = fmaxf(m, __shfl_xor(m, 2));
                m = fmaxf(m, __shfl_xor(m, 4));
                m = fmaxf(m, __shfl_xor(m, 8));
                mx[r] = m;
            }
            int needl = 0;
            #pragma unroll
            for (int r = 0; r < 4; ++r) needl |= (mx[r] > m_run[r] + 8.0f);
            const int need = __any(needl);

            float rr[4];
            if (need) {
                #pragma unroll
                for (int r = 0; r < 4; ++r) {
                    const float m_new = fmaxf(m_run[r], mx[r]);
                    rr[r] = exp2f((m_run[r] - m_new) * LOG2E);
                    m_run[r] = m_new;
                }
            } else {
                #pragma unroll
                for (int r = 0; r < 4; ++r) rr[r] = 1.0f;
            }

            #pragma unroll
            for (int r = 0; r < 4; ++r) {
                const float p0 = exp2f((S[0][r] - m_run[r]) * LOG2E);
                const float p1 = exp2f((S[1][r] - m_run[r]) * LOG2E);
                float sm = p0 + p1;
                sm += __shfl_xor(sm, 1);
                sm += __shfl_xor(sm, 2);
                sm += __shfl_xor(sm, 4);
                sm += __shfl_xor(sm, 8);
                l_run[r] = l_run[r] * rr[r] + sm;
                const int t = tb * 16 + lg * 4 + r;
                P2[PIDX(t, ln)]      = f2bf_bits(p0);
                P2[PIDX(t, 16 + ln)] = f2bf_bits(p1);
            }
            if (ln == 0) {
                #pragma unroll
                for (int r = 0; r < 4; ++r)
                    r_lds[tb * 16 + lg * 4 + r] = rr[r];
            }
            if (lane == 0) nflag[tb] = need ? 1u : 0u;
        }

        // C: V(it) landed (counted; K(it+1) stays in flight); P2/r/flags drain.
        asm volatile("s_waitcnt vmcnt(1) lgkmcnt(0)" ::: "memory");
        __builtin_amdgcn_sched_barrier(0);
        __builtin_amdgcn_s_barrier();
        __builtin_amdgcn_sched_barrier(0);

        // ---- PV on all 8 waves, 32x32x16 MFMAs
        const unsigned f = nflag[0] | nflag[1] | nflag[2] | nflag[3];
        if (f) {
            float4 rq[4];
            #pragma unroll
            for (int q = 0; q < 4; ++q)
                rq[q] = *(const float4*)&r_lds[tq * 32 + 8 * q + 4 * hi];
            #pragma unroll
            for (int ci = 0; ci < 4; ++ci)
                #pragma unroll
                for (int j = 0; j < 16; ++j)
                    acc32[ci][j] *= ((const float*)&rq[j >> 2])[j & 3];
        }

        __builtin_amdgcn_s_setprio(1);
        #pragma unroll
        for (int sk = 0; sk < 2; ++sk) {
            const bf16x8 pa = __builtin_bit_cast(bf16x8,
                *(const us8*)&P2[PIDX(tq * 32 + l31, sk * 16 + hi * 8)]);
            #pragma unroll
            for (int ci = 0; ci < 4; ++ci) {
                const int c = cq * 128 + ci * 32 + l31;
                const bf16x8 bv = __builtin_bit_cast(bf16x8,
                    *(const us8*)&V_s[VIDX2(c, sk * 16 + hi * 8)]);
                acc32[ci] = mfma32(pa, bv, acc32[ci]);
            }
        }
        __builtin_amdgcn_s_setprio(0);
        p ^= 1;
    }

    // ---- publish l, then epilogue: out = gamma * O / l + x
    if (wave < 4 && ln == 0) {
        #pragma unroll
        for (int r = 0; r < 4; ++r)
            l_lds[tb * 16 + lg * 4 + r] = l_run[r];
    }
    __syncthreads();

    const float g = gamma[0];
    float4 il[4];
    #pragma unroll
    for (int q = 0; q < 4; ++q) {
        const float4 lv = *(const float4*)&l_lds[tq * 32 + 8 * q + 4 * hi];
        il[q].x = 1.0f / lv.x; il[q].y = 1.0f / lv.y;
        il[q].z = 1.0f / lv.z; il[q].w = 1.0f / lv.w;
    }

    const float* xb = x + (size_t)b * C_N * T_N;
    float* ob_ = out + (size_t)b * C_N * T_N;

    #pragma unroll
    for (int ci = 0; ci < 4; ++ci) {
        const int c = cq * 128 + ci * 32 + l31;
        const size_t base = (size_t)c * T_N + t0 + tq * 32 + 4 * hi;
        #pragma unroll
        for (int q = 0; q < 4; ++q) {
            const size_t off = base + 8 * q;
            const float4 xv = *(const float4*)&xb[off];
            const float* ilq = (const float*)&il[q];
            float4 o4;
            o4.x = g * acc32[ci][4 * q + 0] * ilq[0] + xv.x;
            o4.y = g * acc32[ci][4 * q + 1] * ilq[1] + xv.y;
            o4.z = g * acc32[ci][4 * q + 2] * ilq[2] + xv.z;
            o4.w = g * acc32[ci][4 * q + 3] * ilq[3] + xv.w;
            *(float4*)&ob_[off] = o4;
        }
    }
}

// ---------------------------------------------------------------------------
extern "C" void kernel_launch(void* const* d_in, const int* in_sizes, int n_in,
                              void* d_out, int out_size, void* d_ws, size_t ws_size,
                              hipStream_t stream)
{
    const float* x     = (const float*)d_in[0];
    const float* wq    = (const float*)d_in[1];
    const float* bq    = (const float*)d_in[2];
    const float* wk    = (const float*)d_in[3];
    const float* bk    = (const float*)d_in[4];
    const float* wv    = (const float*)d_in[5];
    const float* bv    = (const float*)d_in[6];
    const float* gamma = (const float*)d_in[7];
    float* out = (float*)d_out;

    // ws (ushorts): qth|qtl|kth|ktl [b][t][64] | vh [b][c][t] | xt [b][t][512] | whb
    unsigned short* qth = (unsigned short*)d_ws;
    unsigned short* qtl = qth + (size_t)B_N * T_N * 64;
    unsigned short* kth = qtl + (size_t)B_N * T_N * 64;
    unsigned short* ktl = kth + (size_t)B_N * T_N * 64;
    unsigned short* vh  = ktl + (size_t)B_N * T_N * 64;
    unsigned short* xt  = vh  + (size_t)B_N * C_N * T_N;
    unsigned short* whb = xt  + (size_t)B_N * T_N * C_N;

    convert_kernel<<<4136, 256, 0, stream>>>(x, wq, wk, wv, xt, whb);

    qkv_mfma_kernel<<<2560, 512, 0, stream>>>(xt, whb, bq, bk, bv,
                                              qth, qtl, kth, ktl, vh);

    attn_mfma_kernel<<<512, 512, 0, stream>>>(x, qth, qtl, kth, ktl, vh, gamma, out);

    (void)in_sizes; (void)n_in; (void)out_size; (void)ws_size;
}